// Round 10
// baseline (650.502 us; speedup 1.0000x reference)
//
#include <hip/hip_runtime.h>
#include <stdint.h>

// Problem constants (B=2,S=2048,H=1024,F=4096,E=8,K=2)
#define H_DIM 1024
#define F_DIM 4096
#define E_NUM 8
#define T_NUM 4096            // B*S tokens
#define NE    8192            // K * T entries
#define BM    256
#define BN    256
#define BK    64
#define MAXT  40              // true bound: sum_e ceil(n_e/256) <= 39
#define PADM  9984            // 39*256 max padded rows
#define TBY   65536           // gemm1 LDS buffer: A 256x64 (32KB) + B 256x64 (32KB)
#define LDSSZ (2*TBY)         // 128 KB
#define TBY2  49152           // gemm2 LDS buffer: A 128x64 (16KB) @0 + B 256x64 (32KB) @16384
#define LDSSZ2 (2*TBY2)       // 96 KB

#define G1_NWG (MAXT * (F_DIM / BN))        // 640 gemm blocks in k_gemm1
#define G2_NWG (MAXT * 2 * 4 * 2)           // 640: slot x mh x cb x z
#define TRW2_NWG 4096                        // fused w2-trans pair-blocks
#define TRW1_NWG 4096

// meta[] layout (ints)
#define M_NT  0
#define M_PB  1
#define M_CNT 16
#define M_CUR 24
#define M_TE  32    // [40]
#define M_TR  72    // [40]
#define M_INTS 112

typedef float  f32x4  __attribute__((ext_vector_type(4)));
typedef short  bf16x8 __attribute__((ext_vector_type(8)));
typedef __bf16 b16v8  __attribute__((ext_vector_type(8)));
typedef unsigned short u16;
typedef u16    u16x8  __attribute__((ext_vector_type(8)));

#define BAR()   __builtin_amdgcn_s_barrier()
#define FENCE() asm volatile("" ::: "memory")
#define LGKM0() asm volatile("s_waitcnt lgkmcnt(0)" ::: "memory")

__device__ __forceinline__ float gelu_tanh(float v) {
  float u = 0.7978845608028654f * (v + 0.044715f * v * v * v);
  return v / (1.0f + __expf(-2.0f * u));
}

__device__ __forceinline__ float b2f(u16 v) {
  union { float f; unsigned u; } x; x.u = ((unsigned)v) << 16; return x.f;
}

// async global->LDS, 16B per lane; dst wave-uniform base (lane*16 implicit)
__device__ __forceinline__ void gl16(const void* g, void* l) {
  __builtin_amdgcn_global_load_lds(
      (const __attribute__((address_space(1))) unsigned int*)g,
      (__attribute__((address_space(3))) unsigned int*)l, 16, 0, 0);
}

// 64x64 transpose+convert tile body: W fp32 [E][R][C] -> Wt bf16 [E][C][R]
__device__ __forceinline__ void trans_tile(const float* __restrict__ W, u16* __restrict__ Wt,
                                           int R, int C, int e, int bx, int by,
                                           char* L, int tid) {
  int r0 = by * 64, c0 = bx * 64;
  const float* We = W + (size_t)e * R * C;
  u16* Wte = Wt + (size_t)e * R * C;
#pragma unroll
  for (int it = 0; it < 4; ++it) {
    int gi = it * 256 + tid;
    int row = gi >> 4, c4 = gi & 15;
    f32x4 v = *(const f32x4*)(We + (size_t)(r0 + row) * C + c0 + c4 * 4);
    *(f32x4*)(L + row * 256 + ((c4 ^ (row & 15)) * 16)) = v;
  }
  __syncthreads();
#pragma unroll
  for (int s = 0; s < 2; ++s) {
    int chunk = s * 256 + tid;
    int c = chunk >> 3, rb = chunk & 7;
    b16v8 o;
#pragma unroll
    for (int j = 0; j < 8; ++j) {
      int r = rb * 8 + j;
      float f = *(const float*)(L + r * 256 + (((c >> 2) ^ (r & 15)) * 16) + (c & 3) * 4);
      o[j] = (__bf16)f;
    }
    *(b16v8*)(void*)(Wte + (size_t)(c0 + c) * R + r0 + rb * 8) = o;
  }
}

// ---------------- fused prep: init + count + plan + scatter (ONE block) ----------------

__global__ __launch_bounds__(256) void k_moe_prep(
    const int* __restrict__ experts, const float* __restrict__ probs,
    int* tok, float* wgt, int* entpos, int* meta)
{
  int tid = threadIdx.x;
  int lane = tid & 63;
  if (tid < 16) meta[M_CNT + tid] = 0;           // CNT[8] + CUR[8]
  for (int i = tid; i < PADM; i += 256) { tok[i] = 0; wgt[i] = 0.f; }
  __syncthreads();
  // histogram
  for (int c = 0; c < NE / 256; ++c) {
    int i = c * 256 + tid;
    int e = experts[i];
#pragma unroll
    for (int ee = 0; ee < E_NUM; ++ee) {
      unsigned long long bm = __ballot(e == ee);
      if (e == ee && lane == __builtin_ctzll(bm))
        atomicAdd(&meta[M_CNT + ee], __popcll(bm));
    }
  }
  __syncthreads();
  // plan (thread 0)
  if (tid == 0) {
    int pb = 0, idx = 0;
    for (int e = 0; e < E_NUM; ++e) {
      int c = meta[M_CNT + e];
      int nt = (c + BM - 1) / BM;
      meta[M_PB + e] = pb;
      for (int t = 0; t < nt && idx < MAXT; ++t) {
        meta[M_TE + idx] = e; meta[M_TR + idx] = pb + t * BM; ++idx;
      }
      pb += nt * BM;
    }
    meta[M_NT] = idx;
  }
  __syncthreads();
  // scatter
  for (int c = 0; c < NE / 256; ++c) {
    int i = c * 256 + tid;   // i = k*T + t
    int e = experts[i];
    int t = i & (T_NUM - 1);
    float p = probs[i];
#pragma unroll
    for (int ee = 0; ee < E_NUM; ++ee) {
      unsigned long long bm = __ballot(e == ee);
      if (e == ee) {
        int leader = __builtin_ctzll(bm);
        int cnt = __popcll(bm);
        int base = 0;
        if (lane == leader) base = atomicAdd(&meta[M_CUR + ee], cnt);
        base = __shfl(base, leader);
        int rank = __popcll(bm & ((1ull << lane) - 1ull));
        int pos = meta[M_PB + ee] + base + rank;
        tok[pos] = t;
        wgt[pos] = p;
        entpos[i] = pos;
      }
    }
  }
}

// fused: blocks [0, TRW1_NWG) = w1 transpose (2 tiles/block), rest = x fp32->bf16
__global__ __launch_bounds__(512) void k_prep(const float* __restrict__ x, u16* __restrict__ xbf,
                                              const float* __restrict__ w1, u16* __restrict__ w1t) {
  int bid = blockIdx.x;
  if (bid < TRW1_NWG) {
    alignas(16) __shared__ char L[32768];
    int ti = bid * 2 + (threadIdx.x >> 8);
    int e = ti >> 10, rem = ti & 1023;
    int bx = rem & 63, by = rem >> 6;
    trans_tile(w1, w1t, H_DIM, F_DIM, e, bx, by, L + (threadIdx.x >> 8) * 16384, threadIdx.x & 255);
    return;
  }
  int i = (bid - TRW1_NWG) * 512 + threadIdx.x;   // [0, T*H/8)
  const f32x4* xp = (const f32x4*)x;
  f32x4 a = xp[i * 2], b = xp[i * 2 + 1];
  b16v8 o;
  o[0] = (__bf16)a[0]; o[1] = (__bf16)a[1]; o[2] = (__bf16)a[2]; o[3] = (__bf16)a[3];
  o[4] = (__bf16)b[0]; o[5] = (__bf16)b[1]; o[6] = (__bf16)b[2]; o[7] = (__bf16)b[3];
  ((b16v8*)xbf)[i] = o;
}

// standalone w2 transpose (serial fallback path only). grid (C/64, R/64, E)
__global__ __launch_bounds__(256) void k_trans(const float* __restrict__ W, u16* __restrict__ Wt,
                                               int R, int C) {
  alignas(16) __shared__ char L[16384];
  trans_tile(W, Wt, R, C, blockIdx.z, blockIdx.x, blockIdx.y, L, threadIdx.x);
}

// ---------------- GEMM1 core: 256x256 tile, 8-phase pipelined K-loop (round-9, proven) ----------------

#define STG_A(kt, dbb, h)                                                     \
  { gl16(asrc[2*(h)]   + (size_t)(kt) * BK, LDS + (dbb) + (2*(h))   * 8192 + wid * 1024); \
    gl16(asrc[2*(h)+1] + (size_t)(kt) * BK, LDS + (dbb) + (2*(h)+1) * 8192 + wid * 1024); }
#define STG_B(kt, dbb, h)                                                     \
  { gl16(bsrc[2*(h)]   + (size_t)(kt) * BK, LDS + (dbb) + 32768 + (2*(h))   * 8192 + wid * 1024); \
    gl16(bsrc[2*(h)+1] + (size_t)(kt) * BK, LDS + (dbb) + 32768 + (2*(h)+1) * 8192 + wid * 1024); }

#define LD_A(dst, mi, kk)                                                     \
  { int r_ = wr * 128 + (mi) * 16 + (lane & 15);                              \
    int kb_ = (kk) * 64 + ((lane >> 4) << 4);                                 \
    dst = *(const bf16x8*)(Ab_ + r_ * 128 + (kb_ ^ ((r_ & 7) << 4))); }
#define LD_B(dst, ni, kk)                                                     \
  { int c_ = wc * 64 + (ni) * 16 + (lane & 15);                               \
    int kb_ = (kk) * 64 + ((lane >> 4) << 4);                                 \
    dst = *(const bf16x8*)(Bb_ + c_ * 128 + (kb_ ^ ((c_ & 7) << 4))); }

#define MFMA16(p)                                                             \
  __builtin_amdgcn_s_setprio(1);                                              \
  _Pragma("unroll") for (int mm = 0; mm < 2; ++mm)                            \
    _Pragma("unroll") for (int n = 0; n < 4; ++n) {                           \
      acc[2*(p)+mm][n] = __builtin_amdgcn_mfma_f32_16x16x32_bf16(af[mm][0], bfr[n][0], acc[2*(p)+mm][n], 0, 0, 0); \
      acc[2*(p)+mm][n] = __builtin_amdgcn_mfma_f32_16x16x32_bf16(af[mm][1], bfr[n][1], acc[2*(p)+mm][n], 0, 0, 0); \
    }                                                                         \
  __builtin_amdgcn_s_setprio(0);

#define GEMM_KLOOP_8P(NT)                                                     \
  STG_A(0, 0, 0); STG_A(0, 0, 1); STG_B(0, 0, 0); STG_B(0, 0, 1);             \
  STG_B(1, TBY, 0); STG_B(1, TBY, 1);                                         \
  asm volatile("s_waitcnt vmcnt(4)" ::: "memory");                            \
  BAR();                                                                      \
  { int cur = 0;                                                              \
    for (int kt = 0; kt < (NT); ++kt) {                                       \
      const int db = cur * TBY, dn = (cur ^ 1) * TBY;                         \
      const char* Ab_ = LDS + db;                                             \
      const char* Bb_ = LDS + db + 32768;                                     \
      bf16x8 bfr[4][2], af[2][2];                                             \
      /* phase 0 */                                                           \
      FENCE();                                                                \
      _Pragma("unroll") for (int n = 0; n < 4; ++n) { LD_B(bfr[n][0], n, 0); LD_B(bfr[n][1], n, 1); } \
      LD_A(af[0][0], 0, 0); LD_A(af[0][1], 0, 1); LD_A(af[1][0], 1, 0); LD_A(af[1][1], 1, 1); \
      if (kt + 1 < (NT)) STG_A(kt + 1, dn, 0);                                \
      FENCE(); BAR(); LGKM0();                                                \
      MFMA16(0);                                                              \
      FENCE(); BAR();                                                         \
      /* phase 1 */                                                           \
      LD_A(af[0][0], 2, 0); LD_A(af[0][1], 2, 1); LD_A(af[1][0], 3, 0); LD_A(af[1][1], 3, 1); \
      if (kt + 1 < (NT)) STG_A(kt + 1, dn, 1);                                \
      FENCE(); BAR(); LGKM0();                                                \
      MFMA16(1);                                                              \
      FENCE(); BAR();                                                         \
      /* phase 2 */                                                           \
      LD_A(af[0][0], 4, 0); LD_A(af[0][1], 4, 1); LD_A(af[1][0], 5, 0); LD_A(af[1][1], 5, 1); \
      if (kt + 2 < (NT)) STG_B(kt + 2, db, 0);                                \
      FENCE(); BAR(); LGKM0();                                                \
      MFMA16(2);                                                              \
      FENCE(); BAR();                                                         \
      /* phase 3 */                                                           \
      LD_A(af[0][0], 6, 0); LD_A(af[0][1], 6, 1); LD_A(af[1][0], 7, 0); LD_A(af[1][1], 7, 1); \
      if (kt + 2 < (NT)) STG_B(kt + 2, db, 1);                                \
      FENCE(); BAR(); LGKM0();                                                \
      MFMA16(3);                                                              \
      FENCE();                                                                \
      if (kt == (NT) - 2)     { asm volatile("s_waitcnt vmcnt(0)" ::: "memory"); } \
      else if (kt < (NT) - 2) { asm volatile("s_waitcnt vmcnt(4)" ::: "memory"); } \
      BAR();                                                                  \
      cur ^= 1;                                                               \
    } }

// ---------------- GEMM1 (+ fused w2 transpose role blocks) ----------------

__global__ __launch_bounds__(512, 1) void k_gemm1(
    const u16* __restrict__ xbf, const u16* __restrict__ w1t, const float* __restrict__ b1,
    const int* __restrict__ tok, const int* __restrict__ meta, u16* __restrict__ hbuf,
    const float* __restrict__ w2, u16* __restrict__ w2t)
{
  extern __shared__ char LDS[];
  int wg = blockIdx.x;
  if (wg >= G1_NWG) {
    int ti = (wg - G1_NWG) * 2 + (threadIdx.x >> 8);
    int e = ti >> 10, rem = ti & 1023;
    int bx = rem & 15, by = rem >> 4;
    trans_tile(w2, w2t, F_DIM, H_DIM, e, bx, by, LDS + (threadIdx.x >> 8) * 16384, threadIdx.x & 255);
    return;
  }
  int work = (wg & 7) * (G1_NWG / 8) + (wg >> 3);
  int slot = work % MAXT;
  int cbase = (work / MAXT) * BN;
  int nt = meta[M_NT];
  if (slot >= nt) return;
  int e     = meta[M_TE + slot];
  int rbase = meta[M_TR + slot];

  int tid = threadIdx.x;
  int lane = tid & 63;
  int wid = tid >> 6;
  int wr = wid >> 2, wc = wid & 3;     // 2M x 4N waves, 128x64 each
  int cc = tid & 7, rr = tid >> 3;

  const u16* asrc[4]; const u16* bsrc[4];
#pragma unroll
  for (int j = 0; j < 4; ++j) {
    int rj = j * 64 + rr;
    int t = tok[rbase + rj];
    asrc[j] = xbf + (size_t)t * H_DIM + ((cc ^ (rj & 7)) * 8);
    bsrc[j] = w1t + ((size_t)e * F_DIM + cbase + rj) * H_DIM + ((cc ^ (rj & 7)) * 8);
  }

  f32x4 acc[8][4];
#pragma unroll
  for (int m = 0; m < 8; ++m)
#pragma unroll
    for (int n = 0; n < 4; ++n) acc[m][n] = (f32x4){0.f, 0.f, 0.f, 0.f};

  GEMM_KLOOP_8P(H_DIM / BK)   // 16 K-tiles

  // epilogue: bias + gelu + bf16, per-wave LDS bounce (16KB/wave) -> coalesced 16B stores
  float bv[4];
#pragma unroll
  for (int n = 0; n < 4; ++n) bv[n] = b1[e * F_DIM + cbase + wc * 64 + n * 16 + (lane & 15)];
  char* reg = LDS + wid * 16384;
#pragma unroll
  for (int m = 0; m < 8; ++m)
#pragma unroll
    for (int n = 0; n < 4; ++n)
#pragma unroll
      for (int q = 0; q < 4; ++q) {
        float v = acc[m][n][q] + bv[n];
        v = gelu_tanh(v);
        int row4 = ((lane >> 4) << 2) + q;
        int col = n * 16 + (lane & 15);
        *(__bf16*)(reg + m * 2048 + row4 * 128 + col * 2) = (__bf16)v;
      }
#pragma unroll
  for (int q = 0; q < 16; ++q) {
    int m = q >> 1, p = q & 1;
    int byte = p * 1024 + lane * 16;
    u16x8 v = *(const u16x8*)(reg + m * 2048 + byte);
    int row  = p * 8 + (lane >> 3);
    int colb = (lane & 7) * 16;
    size_t grow = (size_t)(rbase + wr * 128 + m * 16 + row);
    size_t gcol = (size_t)(cbase + wc * 64 + (colb >> 1));
    *(u16x8*)(hbuf + grow * F_DIM + gcol) = v;
  }
}

// ---------------- GEMM2: 128x256 half-slot items, 8-phase, split-K=2 ----------------
// LDS buf: A[128 rows][128B] @0 (2x8KB groups), B[256 rows][128B] @16384 (4x8KB).
// Waves 2M x 4N, per-wave 64x64, acc[4][4] (round-2-proven fragment math).
// Stage order per tile t (dbuf d): A(t+1) h0@p0 h1@p1 -> d^1; B(t+2) g01@p2 g23@p3 -> d.
// Boundary vmcnt(4): leaves B(t+2)x4 in flight, guarantees A(t+1)+B(t+1) landed.

#define STG_A2(kt, dbb, j) gl16(asrc[j] + (size_t)(kt) * BK, LDS + (dbb) + (j) * 8192 + wid * 1024);
#define STG_B2(kt, dbb, j) gl16(bsrc[j] + (size_t)(kt) * BK, LDS + (dbb) + 16384 + (j) * 8192 + wid * 1024);

#define LD_A2(dst, mi, kk)                                                    \
  { int r_ = wr * 64 + (mi) * 16 + (lane & 15);                               \
    int kb_ = (kk) * 64 + ((lane >> 4) << 4);                                 \
    dst = *(const bf16x8*)(Ab_ + r_ * 128 + (kb_ ^ ((r_ & 7) << 4))); }
#define LD_B2(dst, ni, kk)                                                    \
  { int c_ = wc * 64 + (ni) * 16 + (lane & 15);                               \
    int kb_ = (kk) * 64 + ((lane >> 4) << 4);                                 \
    dst = *(const bf16x8*)(Bb_ + c_ * 128 + (kb_ ^ ((c_ & 7) << 4))); }

#define MFMA8(mi)                                                             \
  __builtin_amdgcn_s_setprio(1);                                              \
  _Pragma("unroll") for (int n = 0; n < 4; ++n) {                             \
    acc[mi][n] = __builtin_amdgcn_mfma_f32_16x16x32_bf16(af[0], bfr[n][0], acc[mi][n], 0, 0, 0); \
    acc[mi][n] = __builtin_amdgcn_mfma_f32_16x16x32_bf16(af[1], bfr[n][1], acc[mi][n], 0, 0, 0); \
  }                                                                           \
  __builtin_amdgcn_s_setprio(0);

__global__ __launch_bounds__(512, 1) void k_gemm2(
    const u16* __restrict__ hbuf, const u16* __restrict__ w2t, const float* __restrict__ b2,
    const int* __restrict__ meta, u16* __restrict__ ybuf)
{
  extern __shared__ char LDS[];
  // nwg = 640 (%8==0), 80/XCD; decode: slot fastest (same-XCD blocks share B panel)
  int wg = blockIdx.x;
  int work = (wg & 7) * (G2_NWG / 8) + (wg >> 3);
  int zi   = work / 320;
  int rem  = work % 320;
  int slot = rem % MAXT;
  int q    = rem / MAXT;        // 0..7
  int mh   = q & 1;
  int cbase = (q >> 1) * BN;
  int kzb  = zi * (F_DIM / 2);
  int nt = meta[M_NT];
  if (slot >= nt) return;
  int e     = meta[M_TE + slot];
  int rbase = meta[M_TR + slot] + mh * 128;

  int tid = threadIdx.x;
  int lane = tid & 63;
  int wid = tid >> 6;
  int wr = wid >> 2, wc = wid & 3;     // 2M x 4N waves, 64x64 each
  int cc = tid & 7, rr = tid >> 3;

  const u16* asrc[2]; const u16* bsrc[4];
#pragma unroll
  for (int j = 0; j < 2; ++j) {
    int rj = j * 64 + rr;
    asrc[j] = hbuf + (size_t)(rbase + rj) * F_DIM + kzb + ((cc ^ (rj & 7)) * 8);
  }
#pragma unroll
  for (int j = 0; j < 4; ++j) {
    int nj = j * 64 + rr;
    bsrc[j] = w2t + ((size_t)e * H_DIM + cbase + nj) * F_DIM + kzb + ((cc ^ (nj & 7)) * 8);
  }

  f32x4 acc[4][4];
#pragma unroll
  for (int m = 0; m < 4; ++m)
#pragma unroll
    for (int n = 0; n < 4; ++n) acc[m][n] = (f32x4){0.f, 0.f, 0.f, 0.f};

  const int NT = (F_DIM / 2) / BK;   // 32 K-tiles
  // prologue: A(0)x2, B(0)x4, B(1)x4 -> vmcnt(4) leaves B(1) in flight
  STG_A2(0, 0, 0); STG_A2(0, 0, 1);
  STG_B2(0, 0, 0); STG_B2(0, 0, 1); STG_B2(0, 0, 2); STG_B2(0, 0, 3);
  STG_B2(1, TBY2, 0); STG_B2(1, TBY2, 1); STG_B2(1, TBY2, 2); STG_B2(1, TBY2, 3);
  asm volatile("s_waitcnt vmcnt(4)" ::: "memory");
  BAR();
  {
    int cur = 0;
    for (int kt = 0; kt < NT; ++kt) {
      const int db = cur * TBY2, dn = (cur ^ 1) * TBY2;
      const char* Ab_ = LDS + db;
      const char* Bb_ = LDS + db + 16384;
      bf16x8 bfr[4][2], af[2];
      // phase 0: all B frags + A m0; stage A-h0(t+1)
      FENCE();
#pragma unroll
      for (int n = 0; n < 4; ++n) { LD_B2(bfr[n][0], n, 0); LD_B2(bfr[n][1], n, 1); }
      LD_A2(af[0], 0, 0); LD_A2(af[1], 0, 1);
      if (kt + 1 < NT) STG_A2(kt + 1, dn, 0);
      FENCE(); BAR(); LGKM0();
      MFMA8(0);
      FENCE(); BAR();
      // phase 1: A m1; stage A-h1(t+1)
      LD_A2(af[0], 1, 0); LD_A2(af[1], 1, 1);
      if (kt + 1 < NT) STG_A2(kt + 1, dn, 1);
      FENCE(); BAR(); LGKM0();
      MFMA8(1);
      FENCE(); BAR();
      // phase 2: A m2; stage B-g01(t+2) into own dbuf (B reads completed at p0 barrier)
      LD_A2(af[0], 2, 0); LD_A2(af[1], 2, 1);
      if (kt + 2 < NT) { STG_B2(kt + 2, db, 0); STG_B2(kt + 2, db, 1); }
      FENCE(); BAR(); LGKM0();
      MFMA8(2);
      FENCE(); BAR();
      // phase 3: A m3; stage B-g23(t+2)
      LD_A2(af[0], 3, 0); LD_A2(af[1], 3, 1);
      if (kt + 2 < NT) { STG_B2(kt + 2, db, 2); STG_B2(kt + 2, db, 3); }
      FENCE(); BAR(); LGKM0();
      MFMA8(3);
      FENCE();
      if (kt == NT - 2)     { asm volatile("s_waitcnt vmcnt(0)" ::: "memory"); }
      else if (kt < NT - 2) { asm volatile("s_waitcnt vmcnt(4)" ::: "memory"); }
      BAR();
      cur ^= 1;
    }
  }

  // epilogue: (+b2 if zi==0), bf16, per-wave LDS bounce (8KB/wave) -> coalesced stores
  bool z0 = (zi == 0);
  u16* yb = ybuf + (size_t)zi * PADM * H_DIM;
  float bv[4];
#pragma unroll
  for (int n = 0; n < 4; ++n)
    bv[n] = z0 ? b2[e * H_DIM + cbase + wc * 64 + n * 16 + (lane & 15)] : 0.f;
  char* reg = LDS + wid * 8192;
#pragma unroll
  for (int m = 0; m < 4; ++m)
#pragma unroll
    for (int n = 0; n < 4; ++n)
#pragma unroll
      for (int q2 = 0; q2 < 4; ++q2) {
        float v = acc[m][n][q2] + bv[n];
        int row4 = ((lane >> 4) << 2) + q2;
        int col = n * 16 + (lane & 15);
        *(__bf16*)(reg + m * 2048 + row4 * 128 + col * 2) = (__bf16)v;
      }
#pragma unroll
  for (int q2 = 0; q2 < 8; ++q2) {
    int m = q2 >> 1, p = q2 & 1;
    int byte = p * 1024 + lane * 16;
    u16x8 v = *(const u16x8*)(reg + m * 2048 + byte);
    int row  = p * 8 + (lane >> 3);
    int colb = (lane & 7) * 16;
    size_t grow = (size_t)(rbase + wr * 64 + m * 16 + row);
    size_t gcol = (size_t)(cbase + wc * 64 + (colb >> 1));
    *(u16x8*)(yb + grow * H_DIM + gcol) = v;
  }
}

// ---------------- combine: out[t] = sum_k wgt[p_k] * (y0[p_k] + y1[p_k]) ----------------

__global__ __launch_bounds__(256) void k_combine(
    const u16* __restrict__ ybuf, const float* __restrict__ wgt,
    const int* __restrict__ entpos, float* __restrict__ out)
{
  int idx = blockIdx.x * 256 + threadIdx.x;   // T*H/8 threads
  int t = idx >> 7, hc = idx & 127;
  int p0 = entpos[t], p1 = entpos[T_NUM + t];
  float w0 = wgt[p0], w1 = wgt[p1];
  const u16x8* y0 = (const u16x8*)(ybuf);
  const u16x8* y1 = (const u16x8*)(ybuf + (size_t)PADM * H_DIM);
  u16x8 a = y0[(size_t)p0 * (H_DIM / 8) + hc];
  u16x8 b = y1[(size_t)p0 * (H_DIM / 8) + hc];
  u16x8 c = y0[(size_t)p1 * (H_DIM / 8) + hc];
  u16x8 d = y1[(size_t)p1 * (H_DIM / 8) + hc];
  f32x4 o0, o1;
#pragma unroll
  for (int j = 0; j < 4; ++j)
    o0[j] = w0 * (b2f(a[j]) + b2f(b[j])) + w1 * (b2f(c[j]) + b2f(d[j]));
#pragma unroll
  for (int j = 0; j < 4; ++j)
    o1[j] = w0 * (b2f(a[4 + j]) + b2f(b[4 + j])) + w1 * (b2f(c[4 + j]) + b2f(d[4 + j]));
  f32x4* op = (f32x4*)(out + (size_t)t * H_DIM + hc * 8);
  op[0] = o0;
  op[1] = o1;
}

// ---------------- launch ----------------

extern "C" void kernel_launch(void* const* d_in, const int* in_sizes, int n_in,
                              void* d_out, int out_size, void* d_ws, size_t ws_size,
                              hipStream_t stream)
{
  const float* x       = (const float*)d_in[0];
  const float* probs   = (const float*)d_in[1];
  const int*   experts = (const int*)d_in[2];
  const float* w1      = (const float*)d_in[3];
  const float* b1      = (const float*)d_in[4];
  const float* w2      = (const float*)d_in[5];
  const float* b2      = (const float*)d_in[6];
  float* out = (float*)d_out;

  // workspace plan (~198.3 MB base); separate w2t (+67.1 MB) if ws permits
  char* ws = (char*)d_ws;
  size_t off = 0;
  u16*   hbuf = (u16*)(ws + off);  off += (size_t)PADM * F_DIM * sizeof(u16);          // 81.8 MB
  u16*   xbf  = (u16*)(ws + off);  off += (size_t)T_NUM * H_DIM * sizeof(u16);          // 8.4 MB
  u16*   w1t  = (u16*)(ws + off);  off += (size_t)E_NUM * F_DIM * H_DIM * sizeof(u16);  // 67.1 MB
  u16*   ybuf = (u16*)(ws + off);  off += (size_t)2 * PADM * H_DIM * sizeof(u16);       // 40.9 MB
  int*   tok  = (int*)(ws + off);  off += (size_t)PADM * sizeof(int);
  float* wgt  = (float*)(ws + off); off += (size_t)PADM * sizeof(float);
  int*   entpos = (int*)(ws + off); off += (size_t)NE * sizeof(int);
  int*   meta = (int*)(ws + off);  off += M_INTS * sizeof(int);
  size_t w2t_bytes = (size_t)E_NUM * F_DIM * H_DIM * sizeof(u16);
  bool fused = (ws_size >= off + w2t_bytes);
  u16* w2t = fused ? (u16*)(ws + off) : w1t;   // fallback: reuse w1t after gemm1
  (void)in_sizes; (void)n_in;

  hipFuncSetAttribute(reinterpret_cast<const void*>(&k_gemm1),
                      hipFuncAttributeMaxDynamicSharedMemorySize, LDSSZ);
  hipFuncSetAttribute(reinterpret_cast<const void*>(&k_gemm2),
                      hipFuncAttributeMaxDynamicSharedMemorySize, LDSSZ2);

  k_moe_prep<<<dim3(1), 256, 0, stream>>>(experts, probs, tok, wgt, entpos, meta);
  k_prep   <<<dim3(TRW1_NWG + T_NUM * H_DIM / 8 / 512), 512, 0, stream>>>(x, xbf, w1, w1t);
  k_gemm1  <<<dim3(G1_NWG + (fused ? TRW2_NWG : 0)), 512, LDSSZ, stream>>>(
              xbf, w1t, b1, tok, meta, hbuf, w2, w2t);
  if (!fused)
    k_trans<<<dim3(H_DIM / 64, F_DIM / 64, E_NUM), 256, 0, stream>>>(w2, w2t, F_DIM, H_DIM);
  k_gemm2  <<<dim3(G2_NWG), 512, LDSSZ2, stream>>>(hbuf, w2t, b2, meta, ybuf);
  k_combine<<<dim3(T_NUM * H_DIM / 8 / 256), 256, 0, stream>>>(ybuf, wgt, entpos, out);
}

// Round 11
// 347.094 us; speedup vs baseline: 1.8741x; 1.8741x over previous
//
#include <hip/hip_runtime.h>
#include <stdint.h>

// Problem constants (B=2,S=2048,H=1024,F=4096,E=8,K=2)
#define H_DIM 1024
#define F_DIM 4096
#define E_NUM 8
#define T_NUM 4096            // B*S tokens
#define NE    8192            // K * T entries
#define BM    256
#define BN    256
#define BK    64
#define MAXT  40              // true bound: sum_e ceil(n_e/256) <= 39
#define PADM  9984            // 39*256 max padded rows
#define TBY   65536           // gemm1 LDS buffer: A 256x64 (32KB) + B 256x64 (32KB)
#define LDSSZ (2*TBY)         // 128 KB
#define TBY2  49152           // gemm2 LDS buffer: A 128x64 (16KB) @0 + B 256x64 (32KB) @16384
#define LDSSZ2 (2*TBY2)       // 96 KB

#define G1_NWG (MAXT * (F_DIM / BN))        // 640 gemm blocks in k_gemm1
#define G2_NWG (MAXT * 2 * 4 * 2)           // 640: slot x mh x cb x z
#define TRW2_NWG 4096                        // fused w2-trans pair-blocks
#define TRW1_NWG 4096

// meta[] layout (ints)
#define M_NT  0
#define M_PB  1
#define M_CNT 16
#define M_CUR 24
#define M_TE  32    // [40]
#define M_TR  72    // [40]
#define M_INTS 112

typedef float  f32x4  __attribute__((ext_vector_type(4)));
typedef short  bf16x8 __attribute__((ext_vector_type(8)));
typedef __bf16 b16v8  __attribute__((ext_vector_type(8)));
typedef unsigned short u16;
typedef u16    u16x8  __attribute__((ext_vector_type(8)));

#define BAR()   __builtin_amdgcn_s_barrier()
#define FENCE() asm volatile("" ::: "memory")
#define LGKM0() asm volatile("s_waitcnt lgkmcnt(0)" ::: "memory")

__device__ __forceinline__ float gelu_tanh(float v) {
  float u = 0.7978845608028654f * (v + 0.044715f * v * v * v);
  return v / (1.0f + __expf(-2.0f * u));
}

__device__ __forceinline__ float b2f(u16 v) {
  union { float f; unsigned u; } x; x.u = ((unsigned)v) << 16; return x.f;
}

// async global->LDS, 16B per lane; dst wave-uniform base (lane*16 implicit)
__device__ __forceinline__ void gl16(const void* g, void* l) {
  __builtin_amdgcn_global_load_lds(
      (const __attribute__((address_space(1))) unsigned int*)g,
      (__attribute__((address_space(3))) unsigned int*)l, 16, 0, 0);
}

// 64x64 transpose+convert tile body: W fp32 [E][R][C] -> Wt bf16 [E][C][R]
__device__ __forceinline__ void trans_tile(const float* __restrict__ W, u16* __restrict__ Wt,
                                           int R, int C, int e, int bx, int by,
                                           char* L, int tid) {
  int r0 = by * 64, c0 = bx * 64;
  const float* We = W + (size_t)e * R * C;
  u16* Wte = Wt + (size_t)e * R * C;
#pragma unroll
  for (int it = 0; it < 4; ++it) {
    int gi = it * 256 + tid;
    int row = gi >> 4, c4 = gi & 15;
    f32x4 v = *(const f32x4*)(We + (size_t)(r0 + row) * C + c0 + c4 * 4);
    *(f32x4*)(L + row * 256 + ((c4 ^ (row & 15)) * 16)) = v;
  }
  __syncthreads();
#pragma unroll
  for (int s = 0; s < 2; ++s) {
    int chunk = s * 256 + tid;
    int c = chunk >> 3, rb = chunk & 7;
    b16v8 o;
#pragma unroll
    for (int j = 0; j < 8; ++j) {
      int r = rb * 8 + j;
      float f = *(const float*)(L + r * 256 + (((c >> 2) ^ (r & 15)) * 16) + (c & 3) * 4);
      o[j] = (__bf16)f;
    }
    *(b16v8*)(void*)(Wte + (size_t)(c0 + c) * R + r0 + rb * 8) = o;
  }
}

// ---------------- prep kernels (round-9 proven fast parallel versions) ----------------

__global__ void k_init(int* tok, float* wgt, int* meta) {
  int i = blockIdx.x * 256 + threadIdx.x;
  if (i < PADM) { tok[i] = 0; wgt[i] = 0.f; }   // padded rows: token 0, weight 0
  if (i < E_NUM) { meta[M_CNT + i] = 0; meta[M_CUR + i] = 0; }
}

__global__ void k_count(const int* __restrict__ experts, int* meta) {
  int i = blockIdx.x * 256 + threadIdx.x;   // NE threads exactly
  int e = experts[i];
  int lane = threadIdx.x & 63;
#pragma unroll
  for (int ee = 0; ee < E_NUM; ++ee) {
    unsigned long long bm = __ballot(e == ee);
    if (e == ee && lane == __builtin_ctzll(bm))
      atomicAdd(&meta[M_CNT + ee], __popcll(bm));
  }
}

__global__ void k_plan(int* meta) {
  if (threadIdx.x != 0 || blockIdx.x != 0) return;
  int pb = 0, idx = 0;
  for (int e = 0; e < E_NUM; ++e) {
    int c = meta[M_CNT + e];
    int nt = (c + BM - 1) / BM;
    meta[M_PB + e] = pb;
    for (int t = 0; t < nt && idx < MAXT; ++t) {
      meta[M_TE + idx] = e; meta[M_TR + idx] = pb + t * BM; ++idx;
    }
    pb += nt * BM;
  }
  meta[M_NT] = idx;
}

__global__ void k_scatter(const int* __restrict__ experts, const float* __restrict__ probs,
                          int* tok, float* wgt, int* entpos, int* meta) {
  int i = blockIdx.x * 256 + threadIdx.x;   // i = k*T + t
  int e = experts[i];
  int t = i & (T_NUM - 1);
  float p = probs[i];
  int lane = threadIdx.x & 63;
#pragma unroll
  for (int ee = 0; ee < E_NUM; ++ee) {
    unsigned long long bm = __ballot(e == ee);
    if (e == ee) {
      int leader = __builtin_ctzll(bm);
      int cnt = __popcll(bm);
      int base = 0;
      if (lane == leader) base = atomicAdd(&meta[M_CUR + ee], cnt);
      base = __shfl(base, leader);
      int rank = __popcll(bm & ((1ull << lane) - 1ull));
      int pos = meta[M_PB + ee] + base + rank;
      tok[pos] = t;
      wgt[pos] = p;
      entpos[i] = pos;
    }
  }
}

// fused: blocks [0, TRW1_NWG) = w1 transpose (2 tiles/block), rest = x fp32->bf16
__global__ __launch_bounds__(512) void k_prep(const float* __restrict__ x, u16* __restrict__ xbf,
                                              const float* __restrict__ w1, u16* __restrict__ w1t) {
  int bid = blockIdx.x;
  if (bid < TRW1_NWG) {
    alignas(16) __shared__ char L[32768];
    int ti = bid * 2 + (threadIdx.x >> 8);
    int e = ti >> 10, rem = ti & 1023;
    int bx = rem & 63, by = rem >> 6;
    trans_tile(w1, w1t, H_DIM, F_DIM, e, bx, by, L + (threadIdx.x >> 8) * 16384, threadIdx.x & 255);
    return;
  }
  int i = (bid - TRW1_NWG) * 512 + threadIdx.x;   // [0, T*H/8)
  const f32x4* xp = (const f32x4*)x;
  f32x4 a = xp[i * 2], b = xp[i * 2 + 1];
  b16v8 o;
  o[0] = (__bf16)a[0]; o[1] = (__bf16)a[1]; o[2] = (__bf16)a[2]; o[3] = (__bf16)a[3];
  o[4] = (__bf16)b[0]; o[5] = (__bf16)b[1]; o[6] = (__bf16)b[2]; o[7] = (__bf16)b[3];
  ((b16v8*)xbf)[i] = o;
}

// standalone w2 transpose (serial fallback path only). grid (C/64, R/64, E)
__global__ __launch_bounds__(256) void k_trans(const float* __restrict__ W, u16* __restrict__ Wt,
                                               int R, int C) {
  alignas(16) __shared__ char L[16384];
  trans_tile(W, Wt, R, C, blockIdx.z, blockIdx.x, blockIdx.y, L, threadIdx.x);
}

// ---------------- GEMM1 core: 256x256 tile, 8-phase pipelined K-loop ----------------

#define STG_A(kt, dbb, h)                                                     \
  { gl16(asrc[2*(h)]   + (size_t)(kt) * BK, LDS + (dbb) + (2*(h))   * 8192 + wid * 1024); \
    gl16(asrc[2*(h)+1] + (size_t)(kt) * BK, LDS + (dbb) + (2*(h)+1) * 8192 + wid * 1024); }
#define STG_B(kt, dbb, h)                                                     \
  { gl16(bsrc[2*(h)]   + (size_t)(kt) * BK, LDS + (dbb) + 32768 + (2*(h))   * 8192 + wid * 1024); \
    gl16(bsrc[2*(h)+1] + (size_t)(kt) * BK, LDS + (dbb) + 32768 + (2*(h)+1) * 8192 + wid * 1024); }

#define LD_A(dst, mi, kk)                                                     \
  { int r_ = wr * 128 + (mi) * 16 + (lane & 15);                              \
    int kb_ = (kk) * 64 + ((lane >> 4) << 4);                                 \
    dst = *(const bf16x8*)(Ab_ + r_ * 128 + (kb_ ^ ((r_ & 7) << 4))); }
#define LD_B(dst, ni, kk)                                                     \
  { int c_ = wc * 64 + (ni) * 16 + (lane & 15);                               \
    int kb_ = (kk) * 64 + ((lane >> 4) << 4);                                 \
    dst = *(const bf16x8*)(Bb_ + c_ * 128 + (kb_ ^ ((c_ & 7) << 4))); }

#define MFMA16(p)                                                             \
  __builtin_amdgcn_s_setprio(1);                                              \
  _Pragma("unroll") for (int mm = 0; mm < 2; ++mm)                            \
    _Pragma("unroll") for (int n = 0; n < 4; ++n) {                           \
      acc[2*(p)+mm][n] = __builtin_amdgcn_mfma_f32_16x16x32_bf16(af[mm][0], bfr[n][0], acc[2*(p)+mm][n], 0, 0, 0); \
      acc[2*(p)+mm][n] = __builtin_amdgcn_mfma_f32_16x16x32_bf16(af[mm][1], bfr[n][1], acc[2*(p)+mm][n], 0, 0, 0); \
    }                                                                         \
  __builtin_amdgcn_s_setprio(0);

#define GEMM_KLOOP_8P(NT)                                                     \
  STG_A(0, 0, 0); STG_A(0, 0, 1); STG_B(0, 0, 0); STG_B(0, 0, 1);             \
  STG_B(1, TBY, 0); STG_B(1, TBY, 1);                                         \
  asm volatile("s_waitcnt vmcnt(4)" ::: "memory");                            \
  BAR();                                                                      \
  { int cur = 0;                                                              \
    for (int kt = 0; kt < (NT); ++kt) {                                       \
      const int db = cur * TBY, dn = (cur ^ 1) * TBY;                         \
      const char* Ab_ = LDS + db;                                             \
      const char* Bb_ = LDS + db + 32768;                                     \
      bf16x8 bfr[4][2], af[2][2];                                             \
      /* phase 0 */                                                           \
      FENCE();                                                                \
      _Pragma("unroll") for (int n = 0; n < 4; ++n) { LD_B(bfr[n][0], n, 0); LD_B(bfr[n][1], n, 1); } \
      LD_A(af[0][0], 0, 0); LD_A(af[0][1], 0, 1); LD_A(af[1][0], 1, 0); LD_A(af[1][1], 1, 1); \
      if (kt + 1 < (NT)) STG_A(kt + 1, dn, 0);                                \
      FENCE(); BAR(); LGKM0();                                                \
      MFMA16(0);                                                              \
      FENCE(); BAR();                                                         \
      /* phase 1 */                                                           \
      LD_A(af[0][0], 2, 0); LD_A(af[0][1], 2, 1); LD_A(af[1][0], 3, 0); LD_A(af[1][1], 3, 1); \
      if (kt + 1 < (NT)) STG_A(kt + 1, dn, 1);                                \
      FENCE(); BAR(); LGKM0();                                                \
      MFMA16(1);                                                              \
      FENCE(); BAR();                                                         \
      /* phase 2 */                                                           \
      LD_A(af[0][0], 4, 0); LD_A(af[0][1], 4, 1); LD_A(af[1][0], 5, 0); LD_A(af[1][1], 5, 1); \
      if (kt + 2 < (NT)) STG_B(kt + 2, db, 0);                                \
      FENCE(); BAR(); LGKM0();                                                \
      MFMA16(2);                                                              \
      FENCE(); BAR();                                                         \
      /* phase 3 */                                                           \
      LD_A(af[0][0], 6, 0); LD_A(af[0][1], 6, 1); LD_A(af[1][0], 7, 0); LD_A(af[1][1], 7, 1); \
      if (kt + 2 < (NT)) STG_B(kt + 2, db, 1);                                \
      FENCE(); BAR(); LGKM0();                                                \
      MFMA16(3);                                                              \
      FENCE();                                                                \
      if (kt == (NT) - 2)     { asm volatile("s_waitcnt vmcnt(0)" ::: "memory"); } \
      else if (kt < (NT) - 2) { asm volatile("s_waitcnt vmcnt(4)" ::: "memory"); } \
      BAR();                                                                  \
      cur ^= 1;                                                               \
    } }

// ---------------- GEMM1 (+ fused w2 transpose role blocks) ----------------

__global__ __launch_bounds__(512, 1) void k_gemm1(
    const u16* __restrict__ xbf, const u16* __restrict__ w1t, const float* __restrict__ b1,
    const int* __restrict__ tok, const int* __restrict__ meta, u16* __restrict__ hbuf,
    const float* __restrict__ w2, u16* __restrict__ w2t)
{
  extern __shared__ char LDS[];
  int wg = blockIdx.x;
  if (wg >= G1_NWG) {
    int ti = (wg - G1_NWG) * 2 + (threadIdx.x >> 8);
    int e = ti >> 10, rem = ti & 1023;
    int bx = rem & 15, by = rem >> 4;
    trans_tile(w2, w2t, F_DIM, H_DIM, e, bx, by, LDS + (threadIdx.x >> 8) * 16384, threadIdx.x & 255);
    return;
  }
  int work = (wg & 7) * (G1_NWG / 8) + (wg >> 3);
  int slot = work % MAXT;
  int cbase = (work / MAXT) * BN;
  int nt = meta[M_NT];
  if (slot >= nt) return;
  int e     = meta[M_TE + slot];
  int rbase = meta[M_TR + slot];

  int tid = threadIdx.x;
  int lane = tid & 63;
  int wid = tid >> 6;
  int wr = wid >> 2, wc = wid & 3;     // 2M x 4N waves, 128x64 each
  int cc = tid & 7, rr = tid >> 3;

  const u16* asrc[4]; const u16* bsrc[4];
#pragma unroll
  for (int j = 0; j < 4; ++j) {
    int rj = j * 64 + rr;
    int t = tok[rbase + rj];
    asrc[j] = xbf + (size_t)t * H_DIM + ((cc ^ (rj & 7)) * 8);
    bsrc[j] = w1t + ((size_t)e * F_DIM + cbase + rj) * H_DIM + ((cc ^ (rj & 7)) * 8);
  }

  f32x4 acc[8][4];
#pragma unroll
  for (int m = 0; m < 8; ++m)
#pragma unroll
    for (int n = 0; n < 4; ++n) acc[m][n] = (f32x4){0.f, 0.f, 0.f, 0.f};

  GEMM_KLOOP_8P(H_DIM / BK)   // 16 K-tiles

  // epilogue: bias + gelu + bf16, per-wave LDS bounce (16KB/wave) -> coalesced 16B stores
  float bv[4];
#pragma unroll
  for (int n = 0; n < 4; ++n) bv[n] = b1[e * F_DIM + cbase + wc * 64 + n * 16 + (lane & 15)];
  char* reg = LDS + wid * 16384;
#pragma unroll
  for (int m = 0; m < 8; ++m)
#pragma unroll
    for (int n = 0; n < 4; ++n)
#pragma unroll
      for (int q = 0; q < 4; ++q) {
        float v = acc[m][n][q] + bv[n];
        v = gelu_tanh(v);
        int row4 = ((lane >> 4) << 2) + q;
        int col = n * 16 + (lane & 15);
        *(__bf16*)(reg + m * 2048 + row4 * 128 + col * 2) = (__bf16)v;
      }
#pragma unroll
  for (int q = 0; q < 16; ++q) {
    int m = q >> 1, p = q & 1;
    int byte = p * 1024 + lane * 16;
    u16x8 v = *(const u16x8*)(reg + m * 2048 + byte);
    int row  = p * 8 + (lane >> 3);
    int colb = (lane & 7) * 16;
    size_t grow = (size_t)(rbase + wr * 128 + m * 16 + row);
    size_t gcol = (size_t)(cbase + wc * 64 + (colb >> 1));
    *(u16x8*)(hbuf + grow * F_DIM + gcol) = v;
  }
}

// ---------------- GEMM2: 128x256 half-slot items, 8-phase, split-K=2 ----------------
// LDS buf: A[128 rows][128B] @0 (2x8KB groups), B[256 rows][128B] @16384 (4x8KB).
// Waves 2M x 4N, per-wave 64x64, acc[4][4]. Stage order per tile t (dbuf d):
// A(t+1) h0@p0 h1@p1 -> d^1; B(t+2) g01@p2 g23@p3 -> d.
// Boundary vmcnt(4): leaves B(t+2)x4 in flight, guarantees A(t+1)+B(t+1) landed.

#define STG_A2(kt, dbb, j) gl16(asrc[j] + (size_t)(kt) * BK, LDS + (dbb) + (j) * 8192 + wid * 1024);
#define STG_B2(kt, dbb, j) gl16(bsrc[j] + (size_t)(kt) * BK, LDS + (dbb) + 16384 + (j) * 8192 + wid * 1024);

#define LD_A2(dst, mi, kk)                                                    \
  { int r_ = wr * 64 + (mi) * 16 + (lane & 15);                               \
    int kb_ = (kk) * 64 + ((lane >> 4) << 4);                                 \
    dst = *(const bf16x8*)(Ab_ + r_ * 128 + (kb_ ^ ((r_ & 7) << 4))); }
#define LD_B2(dst, ni, kk)                                                    \
  { int c_ = wc * 64 + (ni) * 16 + (lane & 15);                               \
    int kb_ = (kk) * 64 + ((lane >> 4) << 4);                                 \
    dst = *(const bf16x8*)(Bb_ + c_ * 128 + (kb_ ^ ((c_ & 7) << 4))); }

#define MFMA8(mi)                                                             \
  __builtin_amdgcn_s_setprio(1);                                              \
  _Pragma("unroll") for (int n = 0; n < 4; ++n) {                             \
    acc[mi][n] = __builtin_amdgcn_mfma_f32_16x16x32_bf16(af[0], bfr[n][0], acc[mi][n], 0, 0, 0); \
    acc[mi][n] = __builtin_amdgcn_mfma_f32_16x16x32_bf16(af[1], bfr[n][1], acc[mi][n], 0, 0, 0); \
  }                                                                           \
  __builtin_amdgcn_s_setprio(0);

__global__ __launch_bounds__(512, 1) void k_gemm2(
    const u16* __restrict__ hbuf, const u16* __restrict__ w2t, const float* __restrict__ b2,
    const int* __restrict__ meta, u16* __restrict__ ybuf)
{
  extern __shared__ char LDS[];
  // nwg = 640 (%8==0), 80/XCD; decode: slot fastest (same-XCD blocks share B panel)
  int wg = blockIdx.x;
  int work = (wg & 7) * (G2_NWG / 8) + (wg >> 3);
  int zi   = work / 320;
  int rem  = work % 320;
  int slot = rem % MAXT;
  int q    = rem / MAXT;        // 0..7
  int mh   = q & 1;
  int cbase = (q >> 1) * BN;
  int kzb  = zi * (F_DIM / 2);
  int nt = meta[M_NT];
  if (slot >= nt) return;
  int e     = meta[M_TE + slot];
  int rbase = meta[M_TR + slot] + mh * 128;

  int tid = threadIdx.x;
  int lane = tid & 63;
  int wid = tid >> 6;
  int wr = wid >> 2, wc = wid & 3;     // 2M x 4N waves, 64x64 each
  int cc = tid & 7, rr = tid >> 3;

  const u16* asrc[2]; const u16* bsrc[4];
#pragma unroll
  for (int j = 0; j < 2; ++j) {
    int rj = j * 64 + rr;
    asrc[j] = hbuf + (size_t)(rbase + rj) * F_DIM + kzb + ((cc ^ (rj & 7)) * 8);
  }
#pragma unroll
  for (int j = 0; j < 4; ++j) {
    int nj = j * 64 + rr;
    bsrc[j] = w2t + ((size_t)e * H_DIM + cbase + nj) * F_DIM + kzb + ((cc ^ (nj & 7)) * 8);
  }

  f32x4 acc[4][4];
#pragma unroll
  for (int m = 0; m < 4; ++m)
#pragma unroll
    for (int n = 0; n < 4; ++n) acc[m][n] = (f32x4){0.f, 0.f, 0.f, 0.f};

  const int NT = (F_DIM / 2) / BK;   // 32 K-tiles
  // prologue: A(0)x2, B(0)x4, B(1)x4 -> vmcnt(4) leaves B(1) in flight
  STG_A2(0, 0, 0); STG_A2(0, 0, 1);
  STG_B2(0, 0, 0); STG_B2(0, 0, 1); STG_B2(0, 0, 2); STG_B2(0, 0, 3);
  STG_B2(1, TBY2, 0); STG_B2(1, TBY2, 1); STG_B2(1, TBY2, 2); STG_B2(1, TBY2, 3);
  asm volatile("s_waitcnt vmcnt(4)" ::: "memory");
  BAR();
  {
    int cur = 0;
    for (int kt = 0; kt < NT; ++kt) {
      const int db = cur * TBY2, dn = (cur ^ 1) * TBY2;
      const char* Ab_ = LDS + db;
      const char* Bb_ = LDS + db + 16384;
      bf16x8 bfr[4][2], af[2];
      // phase 0: all B frags + A m0; stage A-h0(t+1)
      FENCE();
#pragma unroll
      for (int n = 0; n < 4; ++n) { LD_B2(bfr[n][0], n, 0); LD_B2(bfr[n][1], n, 1); }
      LD_A2(af[0], 0, 0); LD_A2(af[1], 0, 1);
      if (kt + 1 < NT) STG_A2(kt + 1, dn, 0);
      FENCE(); BAR(); LGKM0();
      MFMA8(0);
      FENCE(); BAR();
      // phase 1: A m1; stage A-h1(t+1)
      LD_A2(af[0], 1, 0); LD_A2(af[1], 1, 1);
      if (kt + 1 < NT) STG_A2(kt + 1, dn, 1);
      FENCE(); BAR(); LGKM0();
      MFMA8(1);
      FENCE(); BAR();
      // phase 2: A m2; stage B-g01(t+2) into own dbuf (B reads completed at p0 barrier)
      LD_A2(af[0], 2, 0); LD_A2(af[1], 2, 1);
      if (kt + 2 < NT) { STG_B2(kt + 2, db, 0); STG_B2(kt + 2, db, 1); }
      FENCE(); BAR(); LGKM0();
      MFMA8(2);
      FENCE(); BAR();
      // phase 3: A m3; stage B-g23(t+2)
      LD_A2(af[0], 3, 0); LD_A2(af[1], 3, 1);
      if (kt + 2 < NT) { STG_B2(kt + 2, db, 2); STG_B2(kt + 2, db, 3); }
      FENCE(); BAR(); LGKM0();
      MFMA8(3);
      FENCE();
      if (kt == NT - 2)     { asm volatile("s_waitcnt vmcnt(0)" ::: "memory"); }
      else if (kt < NT - 2) { asm volatile("s_waitcnt vmcnt(4)" ::: "memory"); }
      BAR();
      cur ^= 1;
    }
  }

  // epilogue: (+b2 if zi==0), bf16, per-wave LDS bounce (8KB/wave) -> coalesced stores
  bool z0 = (zi == 0);
  u16* yb = ybuf + (size_t)zi * PADM * H_DIM;
  float bv[4];
#pragma unroll
  for (int n = 0; n < 4; ++n)
    bv[n] = z0 ? b2[e * H_DIM + cbase + wc * 64 + n * 16 + (lane & 15)] : 0.f;
  char* reg = LDS + wid * 8192;
#pragma unroll
  for (int m = 0; m < 4; ++m)
#pragma unroll
    for (int n = 0; n < 4; ++n)
#pragma unroll
      for (int q2 = 0; q2 < 4; ++q2) {
        float v = acc[m][n][q2] + bv[n];
        int row4 = ((lane >> 4) << 2) + q2;
        int col = n * 16 + (lane & 15);
        *(__bf16*)(reg + m * 2048 + row4 * 128 + col * 2) = (__bf16)v;
      }
#pragma unroll
  for (int q2 = 0; q2 < 8; ++q2) {
    int m = q2 >> 1, p = q2 & 1;
    int byte = p * 1024 + lane * 16;
    u16x8 v = *(const u16x8*)(reg + m * 2048 + byte);
    int row  = p * 8 + (lane >> 3);
    int colb = (lane & 7) * 16;
    size_t grow = (size_t)(rbase + wr * 64 + m * 16 + row);
    size_t gcol = (size_t)(cbase + wc * 64 + (colb >> 1));
    *(u16x8*)(yb + grow * H_DIM + gcol) = v;
  }
}

// ---------------- combine: out[t] = sum_k wgt[p_k] * (y0[p_k] + y1[p_k]) ----------------

__global__ __launch_bounds__(256) void k_combine(
    const u16* __restrict__ ybuf, const float* __restrict__ wgt,
    const int* __restrict__ entpos, float* __restrict__ out)
{
  int idx = blockIdx.x * 256 + threadIdx.x;   // T*H/8 threads
  int t = idx >> 7, hc = idx & 127;
  int p0 = entpos[t], p1 = entpos[T_NUM + t];
  float w0 = wgt[p0], w1 = wgt[p1];
  const u16x8* y0 = (const u16x8*)(ybuf);
  const u16x8* y1 = (const u16x8*)(ybuf + (size_t)PADM * H_DIM);
  u16x8 a = y0[(size_t)p0 * (H_DIM / 8) + hc];
  u16x8 b = y1[(size_t)p0 * (H_DIM / 8) + hc];
  u16x8 c = y0[(size_t)p1 * (H_DIM / 8) + hc];
  u16x8 d = y1[(size_t)p1 * (H_DIM / 8) + hc];
  f32x4 o0, o1;
#pragma unroll
  for (int j = 0; j < 4; ++j)
    o0[j] = w0 * (b2f(a[j]) + b2f(b[j])) + w1 * (b2f(c[j]) + b2f(d[j]));
#pragma unroll
  for (int j = 0; j < 4; ++j)
    o1[j] = w0 * (b2f(a[4 + j]) + b2f(b[4 + j])) + w1 * (b2f(c[4 + j]) + b2f(d[4 + j]));
  f32x4* op = (f32x4*)(out + (size_t)t * H_DIM + hc * 8);
  op[0] = o0;
  op[1] = o1;
}

// ---------------- launch ----------------

extern "C" void kernel_launch(void* const* d_in, const int* in_sizes, int n_in,
                              void* d_out, int out_size, void* d_ws, size_t ws_size,
                              hipStream_t stream)
{
  const float* x       = (const float*)d_in[0];
  const float* probs   = (const float*)d_in[1];
  const int*   experts = (const int*)d_in[2];
  const float* w1      = (const float*)d_in[3];
  const float* b1      = (const float*)d_in[4];
  const float* w2      = (const float*)d_in[5];
  const float* b2      = (const float*)d_in[6];
  float* out = (float*)d_out;

  // workspace plan (~198.3 MB base); separate w2t (+67.1 MB) if ws permits
  char* ws = (char*)d_ws;
  size_t off = 0;
  u16*   hbuf = (u16*)(ws + off);  off += (size_t)PADM * F_DIM * sizeof(u16);          // 81.8 MB
  u16*   xbf  = (u16*)(ws + off);  off += (size_t)T_NUM * H_DIM * sizeof(u16);          // 8.4 MB
  u16*   w1t  = (u16*)(ws + off);  off += (size_t)E_NUM * F_DIM * H_DIM * sizeof(u16);  // 67.1 MB
  u16*   ybuf = (u16*)(ws + off);  off += (size_t)2 * PADM * H_DIM * sizeof(u16);       // 40.9 MB
  int*   tok  = (int*)(ws + off);  off += (size_t)PADM * sizeof(int);
  float* wgt  = (float*)(ws + off); off += (size_t)PADM * sizeof(float);
  int*   entpos = (int*)(ws + off); off += (size_t)NE * sizeof(int);
  int*   meta = (int*)(ws + off);  off += M_INTS * sizeof(int);
  size_t w2t_bytes = (size_t)E_NUM * F_DIM * H_DIM * sizeof(u16);
  bool fused = (ws_size >= off + w2t_bytes);
  u16* w2t = fused ? (u16*)(ws + off) : w1t;   // fallback: reuse w1t after gemm1
  (void)in_sizes; (void)n_in;

  hipFuncSetAttribute(reinterpret_cast<const void*>(&k_gemm1),
                      hipFuncAttributeMaxDynamicSharedMemorySize, LDSSZ);
  hipFuncSetAttribute(reinterpret_cast<const void*>(&k_gemm2),
                      hipFuncAttributeMaxDynamicSharedMemorySize, LDSSZ2);

  k_init   <<<dim3((PADM + 255) / 256), 256, 0, stream>>>(tok, wgt, meta);
  k_count  <<<dim3(NE / 256), 256, 0, stream>>>(experts, meta);
  k_plan   <<<1, 1, 0, stream>>>(meta);
  k_scatter<<<dim3(NE / 256), 256, 0, stream>>>(experts, probs, tok, wgt, entpos, meta);
  k_prep   <<<dim3(TRW1_NWG + T_NUM * H_DIM / 8 / 512), 512, 0, stream>>>(x, xbf, w1, w1t);
  k_gemm1  <<<dim3(G1_NWG + (fused ? TRW2_NWG : 0)), 512, LDSSZ, stream>>>(
              xbf, w1t, b1, tok, meta, hbuf, w2, w2t);
  if (!fused)
    k_trans<<<dim3(H_DIM / 64, F_DIM / 64, E_NUM), 256, 0, stream>>>(w2, w2t, F_DIM, H_DIM);
  k_gemm2  <<<dim3(G2_NWG), 512, LDSSZ2, stream>>>(hbuf, w2t, b2, meta, ybuf);
  k_combine<<<dim3(T_NUM * H_DIM / 8 / 256), 256, 0, stream>>>(ybuf, wgt, entpos, out);
}

// Round 12
// 321.689 us; speedup vs baseline: 2.0221x; 1.0790x over previous
//
#include <hip/hip_runtime.h>
#include <stdint.h>

// Problem constants (B=2,S=2048,H=1024,F=4096,E=8,K=2)
#define H_DIM 1024
#define F_DIM 4096
#define E_NUM 8
#define T_NUM 4096            // B*S tokens
#define NE    8192            // K * T entries
#define BM    256
#define BN    256
#define BK    64
#define MAXT  40              // true bound: sum_e ceil(n_e/256) <= 39
#define PADM  9984            // 39*256 max padded rows
#define TBY   65536           // LDS buffer: A 256x64 (32KB) + B 256x64 (32KB)
#define LDSSZ (2*TBY)         // 128 KB

#define G1_NWG (MAXT * (F_DIM / BN))        // 640 gemm blocks in k_gemm1
#define TRW2_NWG 4096                        // fused w2-trans pair-blocks
#define TRW1_NWG 4096

// meta[] layout (ints)
#define M_NT  0
#define M_PB  1
#define M_CNT 16
#define M_CUR 24
#define M_TE  32    // [40]
#define M_TR  72    // [40]
#define M_INTS 112

typedef float  f32x4  __attribute__((ext_vector_type(4)));
typedef short  bf16x8 __attribute__((ext_vector_type(8)));
typedef __bf16 b16v8  __attribute__((ext_vector_type(8)));
typedef unsigned short u16;
typedef u16    u16x8  __attribute__((ext_vector_type(8)));

#define BAR()   __builtin_amdgcn_s_barrier()
#define FENCE() asm volatile("" ::: "memory")
#define LGKM0() asm volatile("s_waitcnt lgkmcnt(0)" ::: "memory")

__device__ __forceinline__ float gelu_tanh(float v) {
  float u = 0.7978845608028654f * (v + 0.044715f * v * v * v);
  return v / (1.0f + __expf(-2.0f * u));
}

__device__ __forceinline__ float b2f(u16 v) {
  union { float f; unsigned u; } x; x.u = ((unsigned)v) << 16; return x.f;
}

// async global->LDS, 16B per lane; dst wave-uniform base (lane*16 implicit)
__device__ __forceinline__ void gl16(const void* g, void* l) {
  __builtin_amdgcn_global_load_lds(
      (const __attribute__((address_space(1))) unsigned int*)g,
      (__attribute__((address_space(3))) unsigned int*)l, 16, 0, 0);
}

// 64x64 transpose+convert tile body: W fp32 [E][R][C] -> Wt bf16 [E][C][R]
__device__ __forceinline__ void trans_tile(const float* __restrict__ W, u16* __restrict__ Wt,
                                           int R, int C, int e, int bx, int by,
                                           char* L, int tid) {
  int r0 = by * 64, c0 = bx * 64;
  const float* We = W + (size_t)e * R * C;
  u16* Wte = Wt + (size_t)e * R * C;
#pragma unroll
  for (int it = 0; it < 4; ++it) {
    int gi = it * 256 + tid;
    int row = gi >> 4, c4 = gi & 15;
    f32x4 v = *(const f32x4*)(We + (size_t)(r0 + row) * C + c0 + c4 * 4);
    *(f32x4*)(L + row * 256 + ((c4 ^ (row & 15)) * 16)) = v;
  }
  __syncthreads();
#pragma unroll
  for (int s = 0; s < 2; ++s) {
    int chunk = s * 256 + tid;
    int c = chunk >> 3, rb = chunk & 7;
    b16v8 o;
#pragma unroll
    for (int j = 0; j < 8; ++j) {
      int r = rb * 8 + j;
      float f = *(const float*)(L + r * 256 + (((c >> 2) ^ (r & 15)) * 16) + (c & 3) * 4);
      o[j] = (__bf16)f;
    }
    *(b16v8*)(void*)(Wte + (size_t)(c0 + c) * R + r0 + rb * 8) = o;
  }
}

// ---------------- prep kernels (proven fast parallel versions) ----------------

__global__ void k_init(int* tok, float* wgt, int* meta) {
  int i = blockIdx.x * 256 + threadIdx.x;
  if (i < PADM) { tok[i] = 0; wgt[i] = 0.f; }   // padded rows: token 0, weight 0
  if (i < E_NUM) { meta[M_CNT + i] = 0; meta[M_CUR + i] = 0; }
}

__global__ void k_count(const int* __restrict__ experts, int* meta) {
  int i = blockIdx.x * 256 + threadIdx.x;   // NE threads exactly
  int e = experts[i];
  int lane = threadIdx.x & 63;
#pragma unroll
  for (int ee = 0; ee < E_NUM; ++ee) {
    unsigned long long bm = __ballot(e == ee);
    if (e == ee && lane == __builtin_ctzll(bm))
      atomicAdd(&meta[M_CNT + ee], __popcll(bm));
  }
}

__global__ void k_plan(int* meta) {
  if (threadIdx.x != 0 || blockIdx.x != 0) return;
  int pb = 0, idx = 0;
  for (int e = 0; e < E_NUM; ++e) {
    int c = meta[M_CNT + e];
    int nt = (c + BM - 1) / BM;
    meta[M_PB + e] = pb;
    for (int t = 0; t < nt && idx < MAXT; ++t) {
      meta[M_TE + idx] = e; meta[M_TR + idx] = pb + t * BM; ++idx;
    }
    pb += nt * BM;
  }
  meta[M_NT] = idx;
}

__global__ void k_scatter(const int* __restrict__ experts, const float* __restrict__ probs,
                          int* tok, float* wgt, int* entpos, int* meta) {
  int i = blockIdx.x * 256 + threadIdx.x;   // i = k*T + t
  int e = experts[i];
  int t = i & (T_NUM - 1);
  float p = probs[i];
  int lane = threadIdx.x & 63;
#pragma unroll
  for (int ee = 0; ee < E_NUM; ++ee) {
    unsigned long long bm = __ballot(e == ee);
    if (e == ee) {
      int leader = __builtin_ctzll(bm);
      int cnt = __popcll(bm);
      int base = 0;
      if (lane == leader) base = atomicAdd(&meta[M_CUR + ee], cnt);
      base = __shfl(base, leader);
      int rank = __popcll(bm & ((1ull << lane) - 1ull));
      int pos = meta[M_PB + ee] + base + rank;
      tok[pos] = t;
      wgt[pos] = p;
      entpos[i] = pos;
    }
  }
}

// fused: blocks [0, TRW1_NWG) = w1 transpose (2 tiles/block), rest = x fp32->bf16
__global__ __launch_bounds__(512) void k_prep(const float* __restrict__ x, u16* __restrict__ xbf,
                                              const float* __restrict__ w1, u16* __restrict__ w1t) {
  int bid = blockIdx.x;
  if (bid < TRW1_NWG) {
    alignas(16) __shared__ char L[32768];
    int ti = bid * 2 + (threadIdx.x >> 8);
    int e = ti >> 10, rem = ti & 1023;
    int bx = rem & 63, by = rem >> 6;
    trans_tile(w1, w1t, H_DIM, F_DIM, e, bx, by, L + (threadIdx.x >> 8) * 16384, threadIdx.x & 255);
    return;
  }
  int i = (bid - TRW1_NWG) * 512 + threadIdx.x;   // [0, T*H/8)
  const f32x4* xp = (const f32x4*)x;
  f32x4 a = xp[i * 2], b = xp[i * 2 + 1];
  b16v8 o;
  o[0] = (__bf16)a[0]; o[1] = (__bf16)a[1]; o[2] = (__bf16)a[2]; o[3] = (__bf16)a[3];
  o[4] = (__bf16)b[0]; o[5] = (__bf16)b[1]; o[6] = (__bf16)b[2]; o[7] = (__bf16)b[3];
  ((b16v8*)xbf)[i] = o;
}

// standalone w2 transpose (serial fallback path only). grid (C/64, R/64, E)
__global__ __launch_bounds__(256) void k_trans(const float* __restrict__ W, u16* __restrict__ Wt,
                                               int R, int C) {
  alignas(16) __shared__ char L[16384];
  trans_tile(W, Wt, R, C, blockIdx.z, blockIdx.x, blockIdx.y, L, threadIdx.x);
}

// ---------------- GEMM core: 256x256 tile, 8-phase pipelined K-loop ----------------
// LDS dbuf: A[256 rows][128B] @0, B likewise @32768; chunk c of row r holds global
// k-chunk c^(r&7) (16B XOR swizzle); staged via global_load_lds (linear dest,
// swizzle folded into per-lane global src). Waves 2M x 4N, per-wave 128x64.
// Stage order per tile t (dbuf d): A(t+1) h0@p0 h1@p1 -> d^1 (A dead since t-1);
// B(t+2) h0@p2 h1@p3 -> d (B reads completed at p0 barrier). Boundary vmcnt(4).

#define STG_A(kt, dbb, h)                                                     \
  { gl16(asrc[2*(h)]   + (size_t)(kt) * BK, LDS + (dbb) + (2*(h))   * 8192 + wid * 1024); \
    gl16(asrc[2*(h)+1] + (size_t)(kt) * BK, LDS + (dbb) + (2*(h)+1) * 8192 + wid * 1024); }
#define STG_B(kt, dbb, h)                                                     \
  { gl16(bsrc[2*(h)]   + (size_t)(kt) * BK, LDS + (dbb) + 32768 + (2*(h))   * 8192 + wid * 1024); \
    gl16(bsrc[2*(h)+1] + (size_t)(kt) * BK, LDS + (dbb) + 32768 + (2*(h)+1) * 8192 + wid * 1024); }

#define LD_A(dst, mi, kk)                                                     \
  { int r_ = wr * 128 + (mi) * 16 + (lane & 15);                              \
    int kb_ = (kk) * 64 + ((lane >> 4) << 4);                                 \
    dst = *(const bf16x8*)(Ab_ + r_ * 128 + (kb_ ^ ((r_ & 7) << 4))); }
#define LD_B(dst, ni, kk)                                                     \
  { int c_ = wc * 64 + (ni) * 16 + (lane & 15);                               \
    int kb_ = (kk) * 64 + ((lane >> 4) << 4);                                 \
    dst = *(const bf16x8*)(Bb_ + c_ * 128 + (kb_ ^ ((c_ & 7) << 4))); }

#define MFMA16(p)                                                             \
  __builtin_amdgcn_s_setprio(1);                                              \
  _Pragma("unroll") for (int mm = 0; mm < 2; ++mm)                            \
    _Pragma("unroll") for (int n = 0; n < 4; ++n) {                           \
      acc[2*(p)+mm][n] = __builtin_amdgcn_mfma_f32_16x16x32_bf16(af[mm][0], bfr[n][0], acc[2*(p)+mm][n], 0, 0, 0); \
      acc[2*(p)+mm][n] = __builtin_amdgcn_mfma_f32_16x16x32_bf16(af[mm][1], bfr[n][1], acc[2*(p)+mm][n], 0, 0, 0); \
    }                                                                         \
  __builtin_amdgcn_s_setprio(0);

#define GEMM_KLOOP_8P(NT)                                                     \
  STG_A(0, 0, 0); STG_A(0, 0, 1); STG_B(0, 0, 0); STG_B(0, 0, 1);             \
  STG_B(1, TBY, 0); STG_B(1, TBY, 1);                                         \
  asm volatile("s_waitcnt vmcnt(4)" ::: "memory");                            \
  BAR();                                                                      \
  { int cur = 0;                                                              \
    for (int kt = 0; kt < (NT); ++kt) {                                       \
      const int db = cur * TBY, dn = (cur ^ 1) * TBY;                         \
      const char* Ab_ = LDS + db;                                             \
      const char* Bb_ = LDS + db + 32768;                                     \
      bf16x8 bfr[4][2], af[2][2];                                             \
      /* phase 0 */                                                           \
      FENCE();                                                                \
      _Pragma("unroll") for (int n = 0; n < 4; ++n) { LD_B(bfr[n][0], n, 0); LD_B(bfr[n][1], n, 1); } \
      LD_A(af[0][0], 0, 0); LD_A(af[0][1], 0, 1); LD_A(af[1][0], 1, 0); LD_A(af[1][1], 1, 1); \
      if (kt + 1 < (NT)) STG_A(kt + 1, dn, 0);                                \
      FENCE(); BAR(); LGKM0();                                                \
      MFMA16(0);                                                              \
      FENCE(); BAR();                                                         \
      /* phase 1 */                                                           \
      LD_A(af[0][0], 2, 0); LD_A(af[0][1], 2, 1); LD_A(af[1][0], 3, 0); LD_A(af[1][1], 3, 1); \
      if (kt + 1 < (NT)) STG_A(kt + 1, dn, 1);                                \
      FENCE(); BAR(); LGKM0();                                                \
      MFMA16(1);                                                              \
      FENCE(); BAR();                                                         \
      /* phase 2 */                                                           \
      LD_A(af[0][0], 4, 0); LD_A(af[0][1], 4, 1); LD_A(af[1][0], 5, 0); LD_A(af[1][1], 5, 1); \
      if (kt + 2 < (NT)) STG_B(kt + 2, db, 0);                                \
      FENCE(); BAR(); LGKM0();                                                \
      MFMA16(2);                                                              \
      FENCE(); BAR();                                                         \
      /* phase 3 */                                                           \
      LD_A(af[0][0], 6, 0); LD_A(af[0][1], 6, 1); LD_A(af[1][0], 7, 0); LD_A(af[1][1], 7, 1); \
      if (kt + 2 < (NT)) STG_B(kt + 2, db, 1);                                \
      FENCE(); BAR(); LGKM0();                                                \
      MFMA16(3);                                                              \
      FENCE();                                                                \
      if (kt == (NT) - 2)     { asm volatile("s_waitcnt vmcnt(0)" ::: "memory"); } \
      else if (kt < (NT) - 2) { asm volatile("s_waitcnt vmcnt(4)" ::: "memory"); } \
      BAR();                                                                  \
      cur ^= 1;                                                               \
    } }

// ---------------- GEMM1 (+ fused w2 transpose role blocks) ----------------

__global__ __launch_bounds__(512, 1) void k_gemm1(
    const u16* __restrict__ xbf, const u16* __restrict__ w1t, const float* __restrict__ b1,
    const int* __restrict__ tok, const int* __restrict__ meta, u16* __restrict__ hbuf,
    const float* __restrict__ w2, u16* __restrict__ w2t)
{
  extern __shared__ char LDS[];
  int wg = blockIdx.x;
  if (wg >= G1_NWG) {
    int ti = (wg - G1_NWG) * 2 + (threadIdx.x >> 8);
    int e = ti >> 10, rem = ti & 1023;
    int bx = rem & 15, by = rem >> 4;
    trans_tile(w2, w2t, F_DIM, H_DIM, e, bx, by, LDS + (threadIdx.x >> 8) * 16384, threadIdx.x & 255);
    return;
  }
  int work = (wg & 7) * (G1_NWG / 8) + (wg >> 3);
  int slot = work % MAXT;
  int cbase = (work / MAXT) * BN;
  int nt = meta[M_NT];
  if (slot >= nt) return;
  int e     = meta[M_TE + slot];
  int rbase = meta[M_TR + slot];

  int tid = threadIdx.x;
  int lane = tid & 63;
  int wid = tid >> 6;
  int wr = wid >> 2, wc = wid & 3;     // 2M x 4N waves, 128x64 each
  int cc = tid & 7, rr = tid >> 3;

  const u16* asrc[4]; const u16* bsrc[4];
#pragma unroll
  for (int j = 0; j < 4; ++j) {
    int rj = j * 64 + rr;
    int t = tok[rbase + rj];
    asrc[j] = xbf + (size_t)t * H_DIM + ((cc ^ (rj & 7)) * 8);
    bsrc[j] = w1t + ((size_t)e * F_DIM + cbase + rj) * H_DIM + ((cc ^ (rj & 7)) * 8);
  }

  f32x4 acc[8][4];
#pragma unroll
  for (int m = 0; m < 8; ++m)
#pragma unroll
    for (int n = 0; n < 4; ++n) acc[m][n] = (f32x4){0.f, 0.f, 0.f, 0.f};

  GEMM_KLOOP_8P(H_DIM / BK)   // 16 K-tiles

  // epilogue: bias + gelu + bf16, per-wave LDS bounce (16KB/wave) -> coalesced 16B stores
  float bv[4];
#pragma unroll
  for (int n = 0; n < 4; ++n) bv[n] = b1[e * F_DIM + cbase + wc * 64 + n * 16 + (lane & 15)];
  char* reg = LDS + wid * 16384;
#pragma unroll
  for (int m = 0; m < 8; ++m)
#pragma unroll
    for (int n = 0; n < 4; ++n)
#pragma unroll
      for (int q = 0; q < 4; ++q) {
        float v = acc[m][n][q] + bv[n];
        v = gelu_tanh(v);
        int row4 = ((lane >> 4) << 2) + q;
        int col = n * 16 + (lane & 15);
        *(__bf16*)(reg + m * 2048 + row4 * 128 + col * 2) = (__bf16)v;
      }
#pragma unroll
  for (int q = 0; q < 16; ++q) {
    int m = q >> 1, p = q & 1;
    int byte = p * 1024 + lane * 16;
    u16x8 v = *(const u16x8*)(reg + m * 2048 + byte);
    int row  = p * 8 + (lane >> 3);
    int colb = (lane & 7) * 16;
    size_t grow = (size_t)(rbase + wr * 128 + m * 16 + row);
    size_t gcol = (size_t)(cbase + wc * 64 + (colb >> 1));
    *(u16x8*)(hbuf + grow * F_DIM + gcol) = v;
  }
}

// ---------------- GEMM2: 256x256 tile, 8-phase, split-K=ZS ----------------
// grid = MAXT*4*ZS (%8==0); decode slot-fastest within XCD chunk. Each (slot,cb,z)
// stages a DISTINCT K-range -> total staged bytes invariant under ZS (unlike M-split).

template<int ZS>
__global__ __launch_bounds__(512, 1) void k_gemm2(
    const u16* __restrict__ hbuf, const u16* __restrict__ w2t, const float* __restrict__ b2,
    const int* __restrict__ meta, u16* __restrict__ ybuf)
{
  extern __shared__ char LDS[];
  const int NWG = MAXT * 4 * ZS;
  int wg = blockIdx.x;
  int work = (wg & 7) * (NWG / 8) + (wg >> 3);
  int zi   = work / (MAXT * 4);
  int rem  = work % (MAXT * 4);
  int slot = rem % MAXT;
  int cbase = (rem / MAXT) * BN;
  int kzb   = zi * (F_DIM / ZS);
  int nt = meta[M_NT];
  if (slot >= nt) return;
  int e     = meta[M_TE + slot];
  int rbase = meta[M_TR + slot];

  int tid = threadIdx.x;
  int lane = tid & 63;
  int wid = tid >> 6;
  int wr = wid >> 2, wc = wid & 3;
  int cc = tid & 7, rr = tid >> 3;

  const u16* asrc[4]; const u16* bsrc[4];
#pragma unroll
  for (int j = 0; j < 4; ++j) {
    int rj = j * 64 + rr;
    asrc[j] = hbuf + (size_t)(rbase + rj) * F_DIM + kzb + ((cc ^ (rj & 7)) * 8);
    bsrc[j] = w2t + ((size_t)e * H_DIM + cbase + rj) * F_DIM + kzb + ((cc ^ (rj & 7)) * 8);
  }

  f32x4 acc[8][4];
#pragma unroll
  for (int m = 0; m < 8; ++m)
#pragma unroll
    for (int n = 0; n < 4; ++n) acc[m][n] = (f32x4){0.f, 0.f, 0.f, 0.f};

  GEMM_KLOOP_8P((F_DIM / ZS) / BK)   // 16 (ZS=4) or 32 (ZS=2) K-tiles

  // epilogue: (+b2 if zi==0), bf16, per-wave LDS bounce -> coalesced stores to ybuf
  bool z0 = (zi == 0);
  u16* yb = ybuf + (size_t)zi * PADM * H_DIM;
  float bv[4];
#pragma unroll
  for (int n = 0; n < 4; ++n)
    bv[n] = z0 ? b2[e * H_DIM + cbase + wc * 64 + n * 16 + (lane & 15)] : 0.f;
  char* reg = LDS + wid * 16384;
#pragma unroll
  for (int m = 0; m < 8; ++m)
#pragma unroll
    for (int n = 0; n < 4; ++n)
#pragma unroll
      for (int q = 0; q < 4; ++q) {
        float v = acc[m][n][q] + bv[n];
        int row4 = ((lane >> 4) << 2) + q;
        int col = n * 16 + (lane & 15);
        *(__bf16*)(reg + m * 2048 + row4 * 128 + col * 2) = (__bf16)v;
      }
#pragma unroll
  for (int q = 0; q < 16; ++q) {
    int m = q >> 1, p = q & 1;
    int byte = p * 1024 + lane * 16;
    u16x8 v = *(const u16x8*)(reg + m * 2048 + byte);
    int row  = p * 8 + (lane >> 3);
    int colb = (lane & 7) * 16;
    size_t grow = (size_t)(rbase + wr * 128 + m * 16 + row);
    size_t gcol = (size_t)(cbase + wc * 64 + (colb >> 1));
    *(u16x8*)(yb + grow * H_DIM + gcol) = v;
  }
}

// ---------------- combine: out[t] = sum_k wgt[p_k] * sum_z y[z][p_k] ----------------

template<int ZS>
__global__ __launch_bounds__(256) void k_combine(
    const u16* __restrict__ ybuf, const float* __restrict__ wgt,
    const int* __restrict__ entpos, float* __restrict__ out)
{
  int idx = blockIdx.x * 256 + threadIdx.x;   // T*H/8 threads
  int t = idx >> 7, hc = idx & 127;
  int p0 = entpos[t], p1 = entpos[T_NUM + t];
  float w0 = wgt[p0], w1 = wgt[p1];
  float s0[8], s1[8];
#pragma unroll
  for (int j = 0; j < 8; ++j) { s0[j] = 0.f; s1[j] = 0.f; }
#pragma unroll
  for (int z = 0; z < ZS; ++z) {
    const u16x8* yz = (const u16x8*)(ybuf + (size_t)z * PADM * H_DIM);
    u16x8 a = yz[(size_t)p0 * (H_DIM / 8) + hc];
    u16x8 b = yz[(size_t)p1 * (H_DIM / 8) + hc];
#pragma unroll
    for (int j = 0; j < 8; ++j) { s0[j] += b2f(a[j]); s1[j] += b2f(b[j]); }
  }
  f32x4 o0, o1;
#pragma unroll
  for (int j = 0; j < 4; ++j) o0[j] = w0 * s0[j] + w1 * s1[j];
#pragma unroll
  for (int j = 0; j < 4; ++j) o1[j] = w0 * s0[4 + j] + w1 * s1[4 + j];
  f32x4* op = (f32x4*)(out + (size_t)t * H_DIM + hc * 8);
  op[0] = o0;
  op[1] = o1;
}

// ---------------- launch ----------------

extern "C" void kernel_launch(void* const* d_in, const int* in_sizes, int n_in,
                              void* d_out, int out_size, void* d_ws, size_t ws_size,
                              hipStream_t stream)
{
  const float* x       = (const float*)d_in[0];
  const float* probs   = (const float*)d_in[1];
  const int*   experts = (const int*)d_in[2];
  const float* w1      = (const float*)d_in[3];
  const float* b1      = (const float*)d_in[4];
  const float* w2      = (const float*)d_in[5];
  const float* b2      = (const float*)d_in[6];
  float* out = (float*)d_out;

  // workspace plan (~198.3 MB base); separate w2t (+67.1 MB) if ws permits
  char* ws = (char*)d_ws;
  size_t off = 0;
  u16*   hbuf = (u16*)(ws + off);  off += (size_t)PADM * F_DIM * sizeof(u16);          // 81.8 MB
  u16*   xbf  = (u16*)(ws + off);  off += (size_t)T_NUM * H_DIM * sizeof(u16);          // 8.4 MB
  u16*   w1t  = (u16*)(ws + off);  off += (size_t)E_NUM * F_DIM * H_DIM * sizeof(u16);  // 67.1 MB
  u16*   ybuf = (u16*)(ws + off);  off += (size_t)2 * PADM * H_DIM * sizeof(u16);       // 40.9 MB
  int*   tok  = (int*)(ws + off);  off += (size_t)PADM * sizeof(int);
  float* wgt  = (float*)(ws + off); off += (size_t)PADM * sizeof(float);
  int*   entpos = (int*)(ws + off); off += (size_t)NE * sizeof(int);
  int*   meta = (int*)(ws + off);  off += M_INTS * sizeof(int);
  size_t w2t_bytes = (size_t)E_NUM * F_DIM * H_DIM * sizeof(u16);
  bool fused = (ws_size >= off + w2t_bytes);
  u16* w2t = fused ? (u16*)(ws + off) : w1t;   // fallback: reuse w1t after gemm1
  // fused path: ybuf4 = [4][PADM][H] bf16 (81.8 MB) overlays w1t+ybuf (108 MB, both
  // dead after gemm1). !fused: w2t aliases w1t -> overlay forbidden -> ZS=2 + ybuf.
  u16* ybuf4 = w1t;
  (void)in_sizes; (void)n_in;

  hipFuncSetAttribute(reinterpret_cast<const void*>(&k_gemm1),
                      hipFuncAttributeMaxDynamicSharedMemorySize, LDSSZ);
  hipFuncSetAttribute(reinterpret_cast<const void*>(&k_gemm2<4>),
                      hipFuncAttributeMaxDynamicSharedMemorySize, LDSSZ);
  hipFuncSetAttribute(reinterpret_cast<const void*>(&k_gemm2<2>),
                      hipFuncAttributeMaxDynamicSharedMemorySize, LDSSZ);

  k_init   <<<dim3((PADM + 255) / 256), 256, 0, stream>>>(tok, wgt, meta);
  k_count  <<<dim3(NE / 256), 256, 0, stream>>>(experts, meta);
  k_plan   <<<1, 1, 0, stream>>>(meta);
  k_scatter<<<dim3(NE / 256), 256, 0, stream>>>(experts, probs, tok, wgt, entpos, meta);
  k_prep   <<<dim3(TRW1_NWG + T_NUM * H_DIM / 8 / 512), 512, 0, stream>>>(x, xbf, w1, w1t);
  k_gemm1  <<<dim3(G1_NWG + (fused ? TRW2_NWG : 0)), 512, LDSSZ, stream>>>(
              xbf, w1t, b1, tok, meta, hbuf, w2, w2t);
  if (fused) {
    k_gemm2<4><<<dim3(MAXT * 4 * 4), 512, LDSSZ, stream>>>(hbuf, w2t, b2, meta, ybuf4);
    k_combine<4><<<dim3(T_NUM * H_DIM / 8 / 256), 256, 0, stream>>>(ybuf4, wgt, entpos, out);
  } else {
    k_trans<<<dim3(H_DIM / 64, F_DIM / 64, E_NUM), 256, 0, stream>>>(w2, w2t, F_DIM, H_DIM);
    k_gemm2<2><<<dim3(MAXT * 4 * 2), 512, LDSSZ, stream>>>(hbuf, w2t, b2, meta, ybuf);
    k_combine<2><<<dim3(T_NUM * H_DIM / 8 / 256), 256, 0, stream>>>(ybuf, wgt, entpos, out);
  }
}

// Round 13
// 319.624 us; speedup vs baseline: 2.0352x; 1.0065x over previous
//
#include <hip/hip_runtime.h>
#include <stdint.h>

// Problem constants (B=2,S=2048,H=1024,F=4096,E=8,K=2)
#define H_DIM 1024
#define F_DIM 4096
#define E_NUM 8
#define T_NUM 4096            // B*S tokens
#define NE    8192            // K * T entries
#define BM    256
#define BN    256
#define BK    64
#define MAXT  40              // true bound: sum_e ceil(n_e/256) <= 39
#define PADM  9984            // 39*256 max padded rows
#define TBY   65536           // LDS buffer: A 256x64 (32KB) + B 256x64 (32KB)
#define LDSSZ (2*TBY)         // 128 KB

#define G1_NWG (MAXT * (F_DIM / BN))        // 640 gemm blocks in k_gemm1
#define TRW2_NWG 2048                        // fused w2-trans blocks (8192 tiles / 4)
#define TRW1_NWG 4096

// meta[] layout (ints)
#define M_NT  0
#define M_PB  1
#define M_CNT 16
#define M_CUR 24
#define M_TE  32    // [40]
#define M_TR  72    // [40]
#define M_INTS 112

typedef float  f32x4  __attribute__((ext_vector_type(4)));
typedef short  bf16x8 __attribute__((ext_vector_type(8)));
typedef __bf16 b16v8  __attribute__((ext_vector_type(8)));
typedef unsigned short u16;
typedef u16    u16x8  __attribute__((ext_vector_type(8)));

#define BAR()   __builtin_amdgcn_s_barrier()
#define FENCE() asm volatile("" ::: "memory")
#define LGKM0() asm volatile("s_waitcnt lgkmcnt(0)" ::: "memory")

__device__ __forceinline__ float gelu_tanh(float v) {
  float u = 0.7978845608028654f * (v + 0.044715f * v * v * v);
  return v / (1.0f + __expf(-2.0f * u));
}

__device__ __forceinline__ float b2f(u16 v) {
  union { float f; unsigned u; } x; x.u = ((unsigned)v) << 16; return x.f;
}

// async global->LDS, 16B per lane; dst wave-uniform base (lane*16 implicit)
__device__ __forceinline__ void gl16(const void* g, void* l) {
  __builtin_amdgcn_global_load_lds(
      (const __attribute__((address_space(1))) unsigned int*)g,
      (__attribute__((address_space(3))) unsigned int*)l, 16, 0, 0);
}

// ---- 64x64 transpose+convert, decomposed (exact split of the proven trans_tile) ----
// W fp32 [E][R][C] -> Wt bf16 [E][C][R]; L = 16KB region, tid in [0,256)

__device__ __forceinline__ void trans_load(const float* __restrict__ We, int C,
                                           int r0, int c0, int tid, f32x4 v[4]) {
#pragma unroll
  for (int it = 0; it < 4; ++it) {
    int gi = it * 256 + tid;
    int row = gi >> 4, c4 = gi & 15;
    v[it] = *(const f32x4*)(We + (size_t)(r0 + row) * C + c0 + c4 * 4);
  }
}
__device__ __forceinline__ void trans_ldswrite(char* L, int tid, const f32x4 v[4]) {
#pragma unroll
  for (int it = 0; it < 4; ++it) {
    int gi = it * 256 + tid;
    int row = gi >> 4, c4 = gi & 15;
    *(f32x4*)(L + row * 256 + ((c4 ^ (row & 15)) * 16)) = v[it];
  }
}
__device__ __forceinline__ void trans_store(u16* __restrict__ Wte, int R,
                                            int r0, int c0, char* L, int tid) {
#pragma unroll
  for (int s = 0; s < 2; ++s) {
    int chunk = s * 256 + tid;
    int c = chunk >> 3, rb = chunk & 7;
    b16v8 o;
#pragma unroll
    for (int j = 0; j < 8; ++j) {
      int r = rb * 8 + j;
      float f = *(const float*)(L + r * 256 + (((c >> 2) ^ (r & 15)) * 16) + (c & 3) * 4);
      o[j] = (__bf16)f;
    }
    *(b16v8*)(void*)(Wte + (size_t)(c0 + c) * R + r0 + rb * 8) = o;
  }
}

__device__ __forceinline__ void trans_tile(const float* __restrict__ W, u16* __restrict__ Wt,
                                           int R, int C, int e, int bx, int by,
                                           char* L, int tid) {
  int r0 = by * 64, c0 = bx * 64;
  const float* We = W + (size_t)e * R * C;
  u16* Wte = Wt + (size_t)e * R * C;
  f32x4 v[4];
  trans_load(We, C, r0, c0, tid, v);
  trans_ldswrite(L, tid, v);
  __syncthreads();
  trans_store(Wte, R, r0, c0, L, tid);
}

// ---------------- prep kernels (proven fast parallel versions) ----------------

__global__ void k_init(int* tok, float* wgt, int* meta) {
  int i = blockIdx.x * 256 + threadIdx.x;
  if (i < PADM) { tok[i] = 0; wgt[i] = 0.f; }   // padded rows: token 0, weight 0
  if (i < E_NUM) { meta[M_CNT + i] = 0; meta[M_CUR + i] = 0; }
}

__global__ void k_count(const int* __restrict__ experts, int* meta) {
  int i = blockIdx.x * 256 + threadIdx.x;   // NE threads exactly
  int e = experts[i];
  int lane = threadIdx.x & 63;
#pragma unroll
  for (int ee = 0; ee < E_NUM; ++ee) {
    unsigned long long bm = __ballot(e == ee);
    if (e == ee && lane == __builtin_ctzll(bm))
      atomicAdd(&meta[M_CNT + ee], __popcll(bm));
  }
}

__global__ void k_plan(int* meta) {
  if (threadIdx.x != 0 || blockIdx.x != 0) return;
  int pb = 0, idx = 0;
  for (int e = 0; e < E_NUM; ++e) {
    int c = meta[M_CNT + e];
    int nt = (c + BM - 1) / BM;
    meta[M_PB + e] = pb;
    for (int t = 0; t < nt && idx < MAXT; ++t) {
      meta[M_TE + idx] = e; meta[M_TR + idx] = pb + t * BM; ++idx;
    }
    pb += nt * BM;
  }
  meta[M_NT] = idx;
}

__global__ void k_scatter(const int* __restrict__ experts, const float* __restrict__ probs,
                          int* tok, float* wgt, int* entpos, int* meta) {
  int i = blockIdx.x * 256 + threadIdx.x;   // i = k*T + t
  int e = experts[i];
  int t = i & (T_NUM - 1);
  float p = probs[i];
  int lane = threadIdx.x & 63;
#pragma unroll
  for (int ee = 0; ee < E_NUM; ++ee) {
    unsigned long long bm = __ballot(e == ee);
    if (e == ee) {
      int leader = __builtin_ctzll(bm);
      int cnt = __popcll(bm);
      int base = 0;
      if (lane == leader) base = atomicAdd(&meta[M_CUR + ee], cnt);
      base = __shfl(base, leader);
      int rank = __popcll(bm & ((1ull << lane) - 1ull));
      int pos = meta[M_PB + ee] + base + rank;
      tok[pos] = t;
      wgt[pos] = p;
      entpos[i] = pos;
    }
  }
}

// fused: blocks [0, TRW1_NWG) = w1 transpose (2 tiles/block), rest = x fp32->bf16
__global__ __launch_bounds__(512) void k_prep(const float* __restrict__ x, u16* __restrict__ xbf,
                                              const float* __restrict__ w1, u16* __restrict__ w1t) {
  int bid = blockIdx.x;
  if (bid < TRW1_NWG) {
    alignas(16) __shared__ char L[32768];
    int ti = bid * 2 + (threadIdx.x >> 8);
    int e = ti >> 10, rem = ti & 1023;
    int bx = rem & 63, by = rem >> 6;
    trans_tile(w1, w1t, H_DIM, F_DIM, e, bx, by, L + (threadIdx.x >> 8) * 16384, threadIdx.x & 255);
    return;
  }
  int i = (bid - TRW1_NWG) * 512 + threadIdx.x;   // [0, T*H/8)
  const f32x4* xp = (const f32x4*)x;
  f32x4 a = xp[i * 2], b = xp[i * 2 + 1];
  b16v8 o;
  o[0] = (__bf16)a[0]; o[1] = (__bf16)a[1]; o[2] = (__bf16)a[2]; o[3] = (__bf16)a[3];
  o[4] = (__bf16)b[0]; o[5] = (__bf16)b[1]; o[6] = (__bf16)b[2]; o[7] = (__bf16)b[3];
  ((b16v8*)xbf)[i] = o;
}

// standalone w2 transpose (serial fallback path only). grid (C/64, R/64, E)
__global__ __launch_bounds__(256) void k_trans(const float* __restrict__ W, u16* __restrict__ Wt,
                                               int R, int C) {
  alignas(16) __shared__ char L[16384];
  trans_tile(W, Wt, R, C, blockIdx.z, blockIdx.x, blockIdx.y, L, threadIdx.x);
}

// ---------------- GEMM core: 256x256 tile, 8-phase pipelined K-loop ----------------
// LDS dbuf: A[256 rows][128B] @0, B likewise @32768; chunk c of row r holds global
// k-chunk c^(r&7) (16B XOR swizzle); staged via global_load_lds (linear dest,
// swizzle folded into per-lane global src). Waves 2M x 4N, per-wave 128x64.
// Stage order per tile t (dbuf d): A(t+1) h0@p0 h1@p1 -> d^1 (A dead since t-1);
// B(t+2) h0@p2 h1@p3 -> d (B reads completed at p0 barrier). Boundary vmcnt(4).

#define STG_A(kt, dbb, h)                                                     \
  { gl16(asrc[2*(h)]   + (size_t)(kt) * BK, LDS + (dbb) + (2*(h))   * 8192 + wid * 1024); \
    gl16(asrc[2*(h)+1] + (size_t)(kt) * BK, LDS + (dbb) + (2*(h)+1) * 8192 + wid * 1024); }
#define STG_B(kt, dbb, h)                                                     \
  { gl16(bsrc[2*(h)]   + (size_t)(kt) * BK, LDS + (dbb) + 32768 + (2*(h))   * 8192 + wid * 1024); \
    gl16(bsrc[2*(h)+1] + (size_t)(kt) * BK, LDS + (dbb) + 32768 + (2*(h)+1) * 8192 + wid * 1024); }

#define LD_A(dst, mi, kk)                                                     \
  { int r_ = wr * 128 + (mi) * 16 + (lane & 15);                              \
    int kb_ = (kk) * 64 + ((lane >> 4) << 4);                                 \
    dst = *(const bf16x8*)(Ab_ + r_ * 128 + (kb_ ^ ((r_ & 7) << 4))); }
#define LD_B(dst, ni, kk)                                                     \
  { int c_ = wc * 64 + (ni) * 16 + (lane & 15);                               \
    int kb_ = (kk) * 64 + ((lane >> 4) << 4);                                 \
    dst = *(const bf16x8*)(Bb_ + c_ * 128 + (kb_ ^ ((c_ & 7) << 4))); }

#define MFMA16(p)                                                             \
  __builtin_amdgcn_s_setprio(1);                                              \
  _Pragma("unroll") for (int mm = 0; mm < 2; ++mm)                            \
    _Pragma("unroll") for (int n = 0; n < 4; ++n) {                           \
      acc[2*(p)+mm][n] = __builtin_amdgcn_mfma_f32_16x16x32_bf16(af[mm][0], bfr[n][0], acc[2*(p)+mm][n], 0, 0, 0); \
      acc[2*(p)+mm][n] = __builtin_amdgcn_mfma_f32_16x16x32_bf16(af[mm][1], bfr[n][1], acc[2*(p)+mm][n], 0, 0, 0); \
    }                                                                         \
  __builtin_amdgcn_s_setprio(0);

#define GEMM_KLOOP_8P(NT)                                                     \
  STG_A(0, 0, 0); STG_A(0, 0, 1); STG_B(0, 0, 0); STG_B(0, 0, 1);             \
  STG_B(1, TBY, 0); STG_B(1, TBY, 1);                                         \
  asm volatile("s_waitcnt vmcnt(4)" ::: "memory");                            \
  BAR();                                                                      \
  { int cur = 0;                                                              \
    for (int kt = 0; kt < (NT); ++kt) {                                       \
      const int db = cur * TBY, dn = (cur ^ 1) * TBY;                         \
      const char* Ab_ = LDS + db;                                             \
      const char* Bb_ = LDS + db + 32768;                                     \
      bf16x8 bfr[4][2], af[2][2];                                             \
      /* phase 0 */                                                           \
      FENCE();                                                                \
      _Pragma("unroll") for (int n = 0; n < 4; ++n) { LD_B(bfr[n][0], n, 0); LD_B(bfr[n][1], n, 1); } \
      LD_A(af[0][0], 0, 0); LD_A(af[0][1], 0, 1); LD_A(af[1][0], 1, 0); LD_A(af[1][1], 1, 1); \
      if (kt + 1 < (NT)) STG_A(kt + 1, dn, 0);                                \
      FENCE(); BAR(); LGKM0();                                                \
      MFMA16(0);                                                              \
      FENCE(); BAR();                                                         \
      /* phase 1 */                                                           \
      LD_A(af[0][0], 2, 0); LD_A(af[0][1], 2, 1); LD_A(af[1][0], 3, 0); LD_A(af[1][1], 3, 1); \
      if (kt + 1 < (NT)) STG_A(kt + 1, dn, 1);                                \
      FENCE(); BAR(); LGKM0();                                                \
      MFMA16(1);                                                              \
      FENCE(); BAR();                                                         \
      /* phase 2 */                                                           \
      LD_A(af[0][0], 4, 0); LD_A(af[0][1], 4, 1); LD_A(af[1][0], 5, 0); LD_A(af[1][1], 5, 1); \
      if (kt + 2 < (NT)) STG_B(kt + 2, db, 0);                                \
      FENCE(); BAR(); LGKM0();                                                \
      MFMA16(2);                                                              \
      FENCE(); BAR();                                                         \
      /* phase 3 */                                                           \
      LD_A(af[0][0], 6, 0); LD_A(af[0][1], 6, 1); LD_A(af[1][0], 7, 0); LD_A(af[1][1], 7, 1); \
      if (kt + 2 < (NT)) STG_B(kt + 2, db, 1);                                \
      FENCE(); BAR(); LGKM0();                                                \
      MFMA16(3);                                                              \
      FENCE();                                                                \
      if (kt == (NT) - 2)     { asm volatile("s_waitcnt vmcnt(0)" ::: "memory"); } \
      else if (kt < (NT) - 2) { asm volatile("s_waitcnt vmcnt(4)" ::: "memory"); } \
      BAR();                                                                  \
      cur ^= 1;                                                               \
    } }

// ---------------- GEMM1 (+ fused pipelined w2 transpose role blocks) ----------------

__global__ __launch_bounds__(512, 1) void k_gemm1(
    const u16* __restrict__ xbf, const u16* __restrict__ w1t, const float* __restrict__ b1,
    const int* __restrict__ tok, const int* __restrict__ meta, u16* __restrict__ hbuf,
    const float* __restrict__ w2, u16* __restrict__ w2t)
{
  extern __shared__ char LDS[];
  int wg = blockIdx.x;
  if (wg >= G1_NWG) {
    // pipelined w2 transpose: 4 tiles/block (2 per 256-group), dbuf'd 16KB LDS halves.
    // w2 [E][F=4096][H=1024] -> w2t [E][H][F]: R=4096, C=1024; 16 bx x 64 by x 8 e
    int g = threadIdx.x >> 8, t256 = threadIdx.x & 255;
    char* L0 = LDS + g * 32768;
    char* L1 = L0 + 16384;
    int ti0 = (wg - G1_NWG) * 4 + g * 2;
    int ti1 = ti0 + 1;
    int e0 = ti0 >> 10, rem0 = ti0 & 1023, r00 = (rem0 >> 4) * 64, c00 = (rem0 & 15) * 64;
    int e1 = ti1 >> 10, rem1 = ti1 & 1023, r01 = (rem1 >> 4) * 64, c01 = (rem1 & 15) * 64;
    const float* We0 = w2 + (size_t)e0 * F_DIM * H_DIM;
    u16*         Wt0 = w2t + (size_t)e0 * F_DIM * H_DIM;
    const float* We1 = w2 + (size_t)e1 * F_DIM * H_DIM;
    u16*         Wt1 = w2t + (size_t)e1 * F_DIM * H_DIM;
    f32x4 v0[4], v1[4];
    trans_load(We0, H_DIM, r00, c00, t256, v0);   // 8 loads in flight
    trans_load(We1, H_DIM, r01, c01, t256, v1);
    trans_ldswrite(L0, t256, v0);
    __syncthreads();
    trans_store(Wt0, F_DIM, r00, c00, L0, t256);  // overlaps v1 load tail
    trans_ldswrite(L1, t256, v1);
    __syncthreads();
    trans_store(Wt1, F_DIM, r01, c01, L1, t256);
    return;
  }
  int work = (wg & 7) * (G1_NWG / 8) + (wg >> 3);
  int slot = work % MAXT;
  int cbase = (work / MAXT) * BN;
  int nt = meta[M_NT];
  if (slot >= nt) return;
  int e     = meta[M_TE + slot];
  int rbase = meta[M_TR + slot];

  int tid = threadIdx.x;
  int lane = tid & 63;
  int wid = tid >> 6;
  int wr = wid >> 2, wc = wid & 3;     // 2M x 4N waves, 128x64 each
  int cc = tid & 7, rr = tid >> 3;

  const u16* asrc[4]; const u16* bsrc[4];
#pragma unroll
  for (int j = 0; j < 4; ++j) {
    int rj = j * 64 + rr;
    int t = tok[rbase + rj];
    asrc[j] = xbf + (size_t)t * H_DIM + ((cc ^ (rj & 7)) * 8);
    bsrc[j] = w1t + ((size_t)e * F_DIM + cbase + rj) * H_DIM + ((cc ^ (rj & 7)) * 8);
  }

  f32x4 acc[8][4];
#pragma unroll
  for (int m = 0; m < 8; ++m)
#pragma unroll
    for (int n = 0; n < 4; ++n) acc[m][n] = (f32x4){0.f, 0.f, 0.f, 0.f};

  GEMM_KLOOP_8P(H_DIM / BK)   // 16 K-tiles

  // epilogue: bias + gelu + bf16, per-wave LDS bounce (16KB/wave) -> coalesced 16B stores
  float bv[4];
#pragma unroll
  for (int n = 0; n < 4; ++n) bv[n] = b1[e * F_DIM + cbase + wc * 64 + n * 16 + (lane & 15)];
  char* reg = LDS + wid * 16384;
#pragma unroll
  for (int m = 0; m < 8; ++m)
#pragma unroll
    for (int n = 0; n < 4; ++n)
#pragma unroll
      for (int q = 0; q < 4; ++q) {
        float v = acc[m][n][q] + bv[n];
        v = gelu_tanh(v);
        int row4 = ((lane >> 4) << 2) + q;
        int col = n * 16 + (lane & 15);
        *(__bf16*)(reg + m * 2048 + row4 * 128 + col * 2) = (__bf16)v;
      }
#pragma unroll
  for (int q = 0; q < 16; ++q) {
    int m = q >> 1, p = q & 1;
    int byte = p * 1024 + lane * 16;
    u16x8 v = *(const u16x8*)(reg + m * 2048 + byte);
    int row  = p * 8 + (lane >> 3);
    int colb = (lane & 7) * 16;
    size_t grow = (size_t)(rbase + wr * 128 + m * 16 + row);
    size_t gcol = (size_t)(cbase + wc * 64 + (colb >> 1));
    *(u16x8*)(hbuf + grow * F_DIM + gcol) = v;
  }
}

// ---------------- GEMM2: 256x256 tile, 8-phase, split-K=ZS ----------------
// grid = MAXT*4*ZS (%8==0); decode slot-fastest within XCD chunk. Each (slot,cb,z)
// stages a DISTINCT K-range -> total staged bytes invariant under ZS (unlike M-split).

template<int ZS>
__global__ __launch_bounds__(512, 1) void k_gemm2(
    const u16* __restrict__ hbuf, const u16* __restrict__ w2t, const float* __restrict__ b2,
    const int* __restrict__ meta, u16* __restrict__ ybuf)
{
  extern __shared__ char LDS[];
  const int NWG = MAXT * 4 * ZS;
  int wg = blockIdx.x;
  int work = (wg & 7) * (NWG / 8) + (wg >> 3);
  int zi   = work / (MAXT * 4);
  int rem  = work % (MAXT * 4);
  int slot = rem % MAXT;
  int cbase = (rem / MAXT) * BN;
  int kzb   = zi * (F_DIM / ZS);
  int nt = meta[M_NT];
  if (slot >= nt) return;
  int e     = meta[M_TE + slot];
  int rbase = meta[M_TR + slot];

  int tid = threadIdx.x;
  int lane = tid & 63;
  int wid = tid >> 6;
  int wr = wid >> 2, wc = wid & 3;
  int cc = tid & 7, rr = tid >> 3;

  const u16* asrc[4]; const u16* bsrc[4];
#pragma unroll
  for (int j = 0; j < 4; ++j) {
    int rj = j * 64 + rr;
    asrc[j] = hbuf + (size_t)(rbase + rj) * F_DIM + kzb + ((cc ^ (rj & 7)) * 8);
    bsrc[j] = w2t + ((size_t)e * H_DIM + cbase + rj) * F_DIM + kzb + ((cc ^ (rj & 7)) * 8);
  }

  f32x4 acc[8][4];
#pragma unroll
  for (int m = 0; m < 8; ++m)
#pragma unroll
    for (int n = 0; n < 4; ++n) acc[m][n] = (f32x4){0.f, 0.f, 0.f, 0.f};

  GEMM_KLOOP_8P((F_DIM / ZS) / BK)   // 16 (ZS=4) or 32 (ZS=2) K-tiles

  // epilogue: (+b2 if zi==0), bf16, per-wave LDS bounce -> coalesced stores to ybuf
  bool z0 = (zi == 0);
  u16* yb = ybuf + (size_t)zi * PADM * H_DIM;
  float bv[4];
#pragma unroll
  for (int n = 0; n < 4; ++n)
    bv[n] = z0 ? b2[e * H_DIM + cbase + wc * 64 + n * 16 + (lane & 15)] : 0.f;
  char* reg = LDS + wid * 16384;
#pragma unroll
  for (int m = 0; m < 8; ++m)
#pragma unroll
    for (int n = 0; n < 4; ++n)
#pragma unroll
      for (int q = 0; q < 4; ++q) {
        float v = acc[m][n][q] + bv[n];
        int row4 = ((lane >> 4) << 2) + q;
        int col = n * 16 + (lane & 15);
        *(__bf16*)(reg + m * 2048 + row4 * 128 + col * 2) = (__bf16)v;
      }
#pragma unroll
  for (int q = 0; q < 16; ++q) {
    int m = q >> 1, p = q & 1;
    int byte = p * 1024 + lane * 16;
    u16x8 v = *(const u16x8*)(reg + m * 2048 + byte);
    int row  = p * 8 + (lane >> 3);
    int colb = (lane & 7) * 16;
    size_t grow = (size_t)(rbase + wr * 128 + m * 16 + row);
    size_t gcol = (size_t)(cbase + wc * 64 + (colb >> 1));
    *(u16x8*)(yb + grow * H_DIM + gcol) = v;
  }
}

// ---------------- combine: out[t] = sum_k wgt[p_k] * sum_z y[z][p_k] ----------------

template<int ZS>
__global__ __launch_bounds__(256) void k_combine(
    const u16* __restrict__ ybuf, const float* __restrict__ wgt,
    const int* __restrict__ entpos, float* __restrict__ out)
{
  int idx = blockIdx.x * 256 + threadIdx.x;   // T*H/8 threads
  int t = idx >> 7, hc = idx & 127;
  int p0 = entpos[t], p1 = entpos[T_NUM + t];
  float w0 = wgt[p0], w1 = wgt[p1];
  float s0[8], s1[8];
#pragma unroll
  for (int j = 0; j < 8; ++j) { s0[j] = 0.f; s1[j] = 0.f; }
#pragma unroll
  for (int z = 0; z < ZS; ++z) {
    const u16x8* yz = (const u16x8*)(ybuf + (size_t)z * PADM * H_DIM);
    u16x8 a = yz[(size_t)p0 * (H_DIM / 8) + hc];
    u16x8 b = yz[(size_t)p1 * (H_DIM / 8) + hc];
#pragma unroll
    for (int j = 0; j < 8; ++j) { s0[j] += b2f(a[j]); s1[j] += b2f(b[j]); }
  }
  f32x4 o0, o1;
#pragma unroll
  for (int j = 0; j < 4; ++j) o0[j] = w0 * s0[j] + w1 * s1[j];
#pragma unroll
  for (int j = 0; j < 4; ++j) o1[j] = w0 * s0[4 + j] + w1 * s1[4 + j];
  f32x4* op = (f32x4*)(out + (size_t)t * H_DIM + hc * 8);
  op[0] = o0;
  op[1] = o1;
}

// ---------------- launch ----------------

extern "C" void kernel_launch(void* const* d_in, const int* in_sizes, int n_in,
                              void* d_out, int out_size, void* d_ws, size_t ws_size,
                              hipStream_t stream)
{
  const float* x       = (const float*)d_in[0];
  const float* probs   = (const float*)d_in[1];
  const int*   experts = (const int*)d_in[2];
  const float* w1      = (const float*)d_in[3];
  const float* b1      = (const float*)d_in[4];
  const float* w2      = (const float*)d_in[5];
  const float* b2      = (const float*)d_in[6];
  float* out = (float*)d_out;

  // workspace plan (~198.3 MB base); separate w2t (+67.1 MB) if ws permits
  char* ws = (char*)d_ws;
  size_t off = 0;
  u16*   hbuf = (u16*)(ws + off);  off += (size_t)PADM * F_DIM * sizeof(u16);          // 81.8 MB
  u16*   xbf  = (u16*)(ws + off);  off += (size_t)T_NUM * H_DIM * sizeof(u16);          // 8.4 MB
  u16*   w1t  = (u16*)(ws + off);  off += (size_t)E_NUM * F_DIM * H_DIM * sizeof(u16);  // 67.1 MB
  u16*   ybuf = (u16*)(ws + off);  off += (size_t)2 * PADM * H_DIM * sizeof(u16);       // 40.9 MB
  int*   tok  = (int*)(ws + off);  off += (size_t)PADM * sizeof(int);
  float* wgt  = (float*)(ws + off); off += (size_t)PADM * sizeof(float);
  int*   entpos = (int*)(ws + off); off += (size_t)NE * sizeof(int);
  int*   meta = (int*)(ws + off);  off += M_INTS * sizeof(int);
  size_t w2t_bytes = (size_t)E_NUM * F_DIM * H_DIM * sizeof(u16);
  bool fused = (ws_size >= off + w2t_bytes);
  u16* w2t = fused ? (u16*)(ws + off) : w1t;   // fallback: reuse w1t after gemm1
  // fused path: ybuf4 = [4][PADM][H] bf16 (81.8 MB) overlays w1t+ybuf (108 MB, both
  // dead after gemm1). !fused: w2t aliases w1t -> overlay forbidden -> ZS=2 + ybuf.
  u16* ybuf4 = w1t;
  (void)in_sizes; (void)n_in;

  hipFuncSetAttribute(reinterpret_cast<const void*>(&k_gemm1),
                      hipFuncAttributeMaxDynamicSharedMemorySize, LDSSZ);
  hipFuncSetAttribute(reinterpret_cast<const void*>(&k_gemm2<4>),
                      hipFuncAttributeMaxDynamicSharedMemorySize, LDSSZ);
  hipFuncSetAttribute(reinterpret_cast<const void*>(&k_gemm2<2>),
                      hipFuncAttributeMaxDynamicSharedMemorySize, LDSSZ);

  k_init   <<<dim3((PADM + 255) / 256), 256, 0, stream>>>(tok, wgt, meta);
  k_count  <<<dim3(NE / 256), 256, 0, stream>>>(experts, meta);
  k_plan   <<<1, 1, 0, stream>>>(meta);
  k_scatter<<<dim3(NE / 256), 256, 0, stream>>>(experts, probs, tok, wgt, entpos, meta);
  k_prep   <<<dim3(TRW1_NWG + T_NUM * H_DIM / 8 / 512), 512, 0, stream>>>(x, xbf, w1, w1t);
  k_gemm1  <<<dim3(G1_NWG + (fused ? TRW2_NWG : 0)), 512, LDSSZ, stream>>>(
              xbf, w1t, b1, tok, meta, hbuf, w2, w2t);
  if (fused) {
    k_gemm2<4><<<dim3(MAXT * 4 * 4), 512, LDSSZ, stream>>>(hbuf, w2t, b2, meta, ybuf4);
    k_combine<4><<<dim3(T_NUM * H_DIM / 8 / 256), 256, 0, stream>>>(ybuf4, wgt, entpos, out);
  } else {
    k_trans<<<dim3(H_DIM / 64, F_DIM / 64, E_NUM), 256, 0, stream>>>(w2, w2t, F_DIM, H_DIM);
    k_gemm2<2><<<dim3(MAXT * 4 * 2), 512, LDSSZ, stream>>>(hbuf, w2t, b2, meta, ybuf);
    k_combine<2><<<dim3(T_NUM * H_DIM / 8 / 256), 256, 0, stream>>>(ybuf, wgt, entpos, out);
  }
}